// Round 9
// baseline (2899.829 us; speedup 1.0000x reference)
//
#include <hip/hip_runtime.h>
#include <hip/hip_fp16.h>

#define TPB 256
#define BN 1024            // coarse buckets (10 low bits), also scatter block size
#define STPB 1024          // threads for scatter/count kernels
#define SCHUNK 16384       // edges per scatter block -> 610 blocks, 16 waves each
#define CAP_L 262144       // cone node list cap (|T2| ~ 85K mean)
#define CAP_E 1572864      // filtered edge cap (~850K mean)

typedef unsigned int uv4 __attribute__((ext_vector_type(4)));

// cnts slots: [0]=running list count, [1]=c4, [2]=c3, [3]=c2, [4]=E2 (filtered edges)

// ---------------- seed: mark idx nodes (tag 1), append to L ----------------
__global__ void seed_mark(const int* __restrict__ idx, int B, int* __restrict__ mark,
                          int* __restrict__ L, int* __restrict__ rowOf, int* __restrict__ cnts) {
    int t = threadIdx.x;
    if (t < B) {
        int u = idx[t];
        if (atomicCAS(&mark[u], 0, 1) == 0) {
            int p = atomicAdd(&cnts[0], 1);
            L[p] = u; rowOf[u] = p;
        }
    }
}

// ---------------- scan A (+ coarse hist): T4 = idx ∪ N_in(idx) ----------------
__global__ void scanA_hist(const int* __restrict__ dst, const int* __restrict__ src, int nE,
                           int* __restrict__ mark, int* __restrict__ L, int* __restrict__ rowOf,
                           int* __restrict__ cnts, int* __restrict__ hist) {
    __shared__ int lh[BN];
    for (int j = threadIdx.x; j < BN; j += blockDim.x) lh[j] = 0;
    __syncthreads();
    int G = gridDim.x * blockDim.x;
    for (int e = blockIdx.x * blockDim.x + threadIdx.x; e < nE; e += G) {
        int d = dst[e];
        atomicAdd(&lh[d >> 10], 1);
        if (mark[d] == 1) {                       // tag-1 (idx) finalized before launch
            int s = src[e];
            if (atomicCAS(&mark[s], 0, 2) == 0) {
                int p = atomicAdd(&cnts[0], 1);
                L[p] = s; rowOf[s] = p;
            }
        }
    }
    __syncthreads();
    for (int j = threadIdx.x; j < BN; j += blockDim.x)
        if (lh[j]) atomicAdd(&hist[j], lh[j]);
}

__global__ void snap(int* __restrict__ cnts, int slot) {
    if (threadIdx.x == 0) cnts[slot] = cnts[0];
}

// ---------------- scans B/C: expand by one hop (tags finalized < newTag) ----------
__global__ void scan_expand(const int* __restrict__ dst, const int* __restrict__ src, int nE,
                            int* __restrict__ mark, int maxTag, int newTag,
                            int* __restrict__ L, int* __restrict__ rowOf, int* __restrict__ cnts) {
    int G = gridDim.x * blockDim.x;
    for (int e = blockIdx.x * blockDim.x + threadIdx.x; e < nE; e += G) {
        int d = dst[e];
        int m = mark[d];
        if (m > 0 && m <= maxTag) {
            int s = src[e];
            if (atomicCAS(&mark[s], 0, newTag) == 0) {
                int p = atomicAdd(&cnts[0], 1);
                L[p] = s; rowOf[s] = p;
            }
        }
    }
}

// ---------------- scan D: filter edges with dst in cone; wave-aggregated append ------
__global__ void scan_filter(const int* __restrict__ dst, const int* __restrict__ src, int nE,
                            const int* __restrict__ mark, const int* __restrict__ rowOf,
                            int* __restrict__ fe_row, int* __restrict__ fe_src,
                            int* __restrict__ rcnt, int* __restrict__ cnts) {
    int G = gridDim.x * blockDim.x;
    int tid = blockIdx.x * blockDim.x + threadIdx.x;
    int lane = threadIdx.x & 63;
    int iters = (nE + G - 1) / G;
    for (int i = 0; i < iters; ++i) {
        int e = tid + i * G;
        int d = 0, r = 0, s = 0;
        bool hit = false;
        if (e < nE) { d = dst[e]; hit = (mark[d] != 0); }
        unsigned long long mb = __ballot(hit);
        if (hit) { r = rowOf[d]; s = src[e]; }
        int cnt = __popcll(mb);
        int base = 0;
        if (lane == 0 && cnt) base = atomicAdd(&cnts[4], cnt);
        base = __shfl(base, 0, 64);
        if (hit) {
            int off = __popcll(mb & ((1ULL << lane) - 1));
            int j = base + off;
            fe_row[j] = r;
            fe_src[j] = s;
            atomicAdd(&rcnt[r], 1);
        }
    }
}

// ---------------- exclusive scan of 1024 bucket counts (degrees path) ----------------
__global__ void scan1024(const int* __restrict__ hist, int* __restrict__ bucketOff,
                         int* __restrict__ tails, int nE) {
    __shared__ int lds[BN];
    int t = threadIdx.x;
    int v = hist[t];
    lds[t] = v;
    __syncthreads();
    for (int off = 1; off < BN; off <<= 1) {
        int u = (t >= off) ? lds[t - off] : 0;
        __syncthreads();
        lds[t] += u;
        __syncthreads();
    }
    int excl = lds[t] - v;
    bucketOff[t] = excl;
    tails[t] = excl;
    if (t == BN - 1) bucketOff[BN] = lds[BN - 1];
}

// ---------------- scatter dstLow10 as u16 into coarse buckets (degrees only) ---------
__global__ __launch_bounds__(STPB) void scatter_u16(const int* __restrict__ dst,
                                                    int* __restrict__ tails,
                                                    unsigned short* __restrict__ bdata, int nE) {
    __shared__ int hist[BN];
    __shared__ int cbase[BN];
    int t = threadIdx.x;
    long base = (long)blockIdx.x * SCHUNK;
    int m = (int)(((long)nE - base < SCHUNK) ? (nE - base) : SCHUNK);
    hist[t] = 0;
    __syncthreads();
    for (int k = t; k < m; k += STPB) atomicAdd(&hist[dst[base + k] >> 10], 1);
    __syncthreads();
    int h = hist[t];
    cbase[t] = h ? atomicAdd(&tails[t], h) : 0;
    __syncthreads();
    hist[t] = 0;
    __syncthreads();
    for (int k = t; k < m; k += STPB) {
        int d = dst[base + k];
        int b = d >> 10;
        int r = atomicAdd(&hist[b], 1);
        bdata[cbase[b] + r] = (unsigned short)(d & (BN - 1));
    }
}

// ---------------- per-bucket degree count -> dis ----------------
__global__ __launch_bounds__(STPB) void count_u16(const unsigned short* __restrict__ bdata,
                                                  const int* __restrict__ bucketOff,
                                                  float* __restrict__ dis, int n) {
    __shared__ int cnt[BN];
    int b = blockIdx.x, t = threadIdx.x;
    cnt[t] = 0;
    __syncthreads();
    int e0 = bucketOff[b], e1 = bucketOff[b + 1];
    for (int k = e0 + t; k < e1; k += STPB) atomicAdd(&cnt[bdata[k]], 1);
    __syncthreads();
    int node = (b << 10) + t;
    if (node < n) dis[node] = rsqrtf((float)cnt[t] + 1.0f);
}

// ---------------- mini-CSR scan (rcnt[0..c2) -> mrp) ----------------
__global__ void scan_blocks(const int* __restrict__ rcnt, int* __restrict__ mrp,
                            int* __restrict__ bsum, const int* __restrict__ cnts) {
    __shared__ int lds[TPB];
    int c2 = cnts[3];
    int i = blockIdx.x * TPB + threadIdx.x;
    int v = (i < c2) ? rcnt[i] : 0;
    lds[threadIdx.x] = v;
    __syncthreads();
#pragma unroll
    for (int off = 1; off < TPB; off <<= 1) {
        int t = (threadIdx.x >= off) ? lds[threadIdx.x - off] : 0;
        __syncthreads();
        lds[threadIdx.x] += t;
        __syncthreads();
    }
    if (i < c2) mrp[i] = lds[threadIdx.x] - v;
    if (threadIdx.x == TPB - 1) bsum[blockIdx.x] = lds[TPB - 1];
}

__global__ void scan_bsum(int* __restrict__ bsum, int nb) {
    __shared__ int lds[TPB];
    int carry = 0;
    for (int base = 0; base < nb; base += TPB) {
        int i = base + threadIdx.x;
        int v = (i < nb) ? bsum[i] : 0;
        lds[threadIdx.x] = v;
        __syncthreads();
        for (int off = 1; off < TPB; off <<= 1) {
            int t = (threadIdx.x >= off) ? lds[threadIdx.x - off] : 0;
            __syncthreads();
            lds[threadIdx.x] += t;
            __syncthreads();
        }
        int incl = lds[threadIdx.x];
        if (i < nb) bsum[i] = carry + incl - v;
        carry += lds[TPB - 1];
        __syncthreads();
    }
}

__global__ void add_off(int* __restrict__ mrp, const int* __restrict__ bsum,
                        const int* __restrict__ cnts) {
    int i = blockIdx.x * TPB + threadIdx.x;
    int c2 = cnts[3];
    if (i < c2) mrp[i] += bsum[blockIdx.x];
    if (i == 0) mrp[c2] = cnts[4];
}

// ---------------- fill mini-CSR ----------------
__global__ void fill_mcol(const int* __restrict__ fe_row, const int* __restrict__ fe_src,
                          const int* __restrict__ mrp, int* __restrict__ cursor,
                          int* __restrict__ mcol, const int* __restrict__ cnts) {
    int E2 = cnts[4];
    int G = gridDim.x * blockDim.x;
    for (int j = blockIdx.x * blockDim.x + threadIdx.x; j < E2; j += G) {
        int r = fe_row[j];
        int pos = atomicAdd(&cursor[r], 1);
        mcol[mrp[r] + pos] = fe_src[j];
    }
}

union H8 { uv4 u; __half2 h2[4]; };

// ---------------- layer 1 (all nodes): hs = (x*W1)*dis  (fp16x8) ----------------
__global__ void node_l1(const float* __restrict__ x, const float* __restrict__ W1,
                        const float* __restrict__ dis, __half* __restrict__ hs, int n) {
    int i = blockIdx.x * blockDim.x + threadIdx.x;
    if (i >= n) return;
    float xd = x[i] * dis[i];
    float4 w0 = ((const float4*)W1)[0];
    float4 w1 = ((const float4*)W1)[1];
    H8 o;
    o.h2[0] = __floats2half2_rn(xd * w0.x, xd * w0.y);
    o.h2[1] = __floats2half2_rn(xd * w0.z, xd * w0.w);
    o.h2[2] = __floats2half2_rn(xd * w1.x, xd * w1.y);
    o.h2[3] = __floats2half2_rn(xd * w1.z, xd * w1.w);
    ((uv4*)hs)[i] = o.u;
}

// ---------------- fused pull + node transform over cone prefix [0, cnts[slot]) --------
// dense row tid: g = dis[u]*(sum hs_in[mcol] + hs_in[u]); t = relu(g+b);
// hs_out[u] = (t @ W)*dis[u]
__global__ void pull_list(const int* __restrict__ L, const int* __restrict__ cnts, int slot,
                          const int* __restrict__ mrp, const int* __restrict__ mcol,
                          const float* __restrict__ dis, const __half* __restrict__ hs_in,
                          const float* __restrict__ bias, const float* __restrict__ W,
                          __half* __restrict__ hs_out) {
    int tid = blockIdx.x * blockDim.x + threadIdx.x;
    if (tid >= cnts[slot]) return;
    int u = L[tid];
    const uv4* hv = (const uv4*)hs_in;
    H8 p; p.u = hv[u];                       // self term
    float2 a0 = __half22float2(p.h2[0]);
    float2 a1 = __half22float2(p.h2[1]);
    float2 a2 = __half22float2(p.h2[2]);
    float2 a3 = __half22float2(p.h2[3]);
    int s = mrp[tid], e = mrp[tid + 1];
    for (int k = s; k < e; ++k) {
        H8 q; q.u = hv[mcol[k]];
        float2 b0 = __half22float2(q.h2[0]);
        float2 b1 = __half22float2(q.h2[1]);
        float2 b2 = __half22float2(q.h2[2]);
        float2 b3 = __half22float2(q.h2[3]);
        a0.x += b0.x; a0.y += b0.y; a1.x += b1.x; a1.y += b1.y;
        a2.x += b2.x; a2.y += b2.y; a3.x += b3.x; a3.y += b3.y;
    }
    float d = dis[u];
    float t[8] = {a0.x * d, a0.y * d, a1.x * d, a1.y * d,
                  a2.x * d, a2.y * d, a3.x * d, a3.y * d};
#pragma unroll
    for (int k = 0; k < 8; ++k) {
        float v = t[k] + bias[k];
        t[k] = v > 0.0f ? v : 0.0f;
    }
    float h[8];
#pragma unroll
    for (int j = 0; j < 8; ++j) {
        float acc = 0.0f;
#pragma unroll
        for (int k = 0; k < 8; ++k) acc += t[k] * W[k * 8 + j];
        h[j] = acc * d;
    }
    H8 o;
    o.h2[0] = __floats2half2_rn(h[0], h[1]);
    o.h2[1] = __floats2half2_rn(h[2], h[3]);
    o.h2[2] = __floats2half2_rn(h[4], h[5]);
    o.h2[3] = __floats2half2_rn(h[6], h[7]);
    ((uv4*)hs_out)[u] = o.u;
}

// ---------------- final: out[t][:] = dis*(sum+self) + b4, for the idx nodes ------
__global__ void pull_final(const int* __restrict__ idx, int B, const int* __restrict__ rowOf,
                           const int* __restrict__ mrp, const int* __restrict__ mcol,
                           const float* __restrict__ dis, const __half* __restrict__ hs_in,
                           const float* __restrict__ b4, float* __restrict__ out) {
    int t = blockIdx.x * blockDim.x + threadIdx.x;
    if (t >= B) return;
    int u = idx[t];
    int rr = rowOf[u];
    const uv4* hv = (const uv4*)hs_in;
    H8 p; p.u = hv[u];
    float2 a0 = __half22float2(p.h2[0]);
    float2 a1 = __half22float2(p.h2[1]);
    float2 a2 = __half22float2(p.h2[2]);
    float2 a3 = __half22float2(p.h2[3]);
    int s = mrp[rr], e = mrp[rr + 1];
    for (int k = s; k < e; ++k) {
        H8 q; q.u = hv[mcol[k]];
        float2 b0 = __half22float2(q.h2[0]);
        float2 b1 = __half22float2(q.h2[1]);
        float2 b2 = __half22float2(q.h2[2]);
        float2 b3 = __half22float2(q.h2[3]);
        a0.x += b0.x; a0.y += b0.y; a1.x += b1.x; a1.y += b1.y;
        a2.x += b2.x; a2.y += b2.y; a3.x += b3.x; a3.y += b3.y;
    }
    float d = dis[u];
    float* op = out + (size_t)t * 8;
    op[0] = a0.x * d + b4[0]; op[1] = a0.y * d + b4[1];
    op[2] = a1.x * d + b4[2]; op[3] = a1.y * d + b4[3];
    op[4] = a2.x * d + b4[4]; op[5] = a2.y * d + b4[5];
    op[6] = a3.x * d + b4[6]; op[7] = a3.y * d + b4[7];
}

extern "C" void kernel_launch(void* const* d_in, const int* in_sizes, int n_in,
                              void* d_out, int out_size, void* d_ws, size_t ws_size,
                              hipStream_t stream) {
    const float* x   = (const float*)d_in[0];
    const int*   ei  = (const int*)d_in[1];
    const int*   idx = (const int*)d_in[2];
    const float* W1  = (const float*)d_in[3];
    const float* b1  = (const float*)d_in[4];
    const float* W2  = (const float*)d_in[5];
    const float* b2  = (const float*)d_in[6];
    const float* W3  = (const float*)d_in[7];
    const float* b3  = (const float*)d_in[8];
    const float* W4  = (const float*)d_in[9];
    const float* b4  = (const float*)d_in[10];

    const int n = in_sizes[0];      // 1,000,000 nodes (n <= 2^20 for bucketing)
    const int E = in_sizes[1] / 2;  // 10,000,000 edges
    const int B = in_sizes[2];      // 64 graphs

    const int* src = ei;
    const int* dst = ei + E;

    // workspace (int elements, regions multiple-of-4 aligned):
    size_t o_mark   = 0;
    size_t o_rowOf  = o_mark   + (size_t)n;
    size_t o_dis    = o_rowOf  + (size_t)n;
    size_t o_hsA    = o_dis    + (size_t)n;
    size_t o_hsB    = o_hsA    + (size_t)n * 4;
    size_t o_L      = o_hsB    + (size_t)n * 4;
    size_t o_feR    = o_L      + CAP_L;
    size_t o_feS    = o_feR    + CAP_E;
    size_t o_mrp    = o_feS    + CAP_E;
    size_t o_rcnt   = o_mrp    + CAP_L + 8;
    size_t o_cursor = o_rcnt   + CAP_L;
    size_t o_mcol   = o_cursor + CAP_L;
    size_t o_u16    = o_mcol   + CAP_E;
    size_t o_small  = o_u16    + (size_t)E / 2 + 4;

    int*            mark     = (int*)d_ws + o_mark;
    int*            rowOf    = (int*)d_ws + o_rowOf;
    float*          dis      = (float*)d_ws + o_dis;
    __half*         hsA      = (__half*)((int*)d_ws + o_hsA);
    __half*         hsB      = (__half*)((int*)d_ws + o_hsB);
    int*            L        = (int*)d_ws + o_L;
    int*            fe_row   = (int*)d_ws + o_feR;
    int*            fe_src   = (int*)d_ws + o_feS;
    int*            mrp      = (int*)d_ws + o_mrp;
    int*            rcnt     = (int*)d_ws + o_rcnt;
    int*            cursor   = (int*)d_ws + o_cursor;
    int*            mcol     = (int*)d_ws + o_mcol;
    unsigned short* bdata    = (unsigned short*)((int*)d_ws + o_u16);
    int*            hist     = (int*)d_ws + o_small;
    int*            bucketOff= hist + BN;
    int*            tails    = bucketOff + BN + 8;
    int*            bsum     = tails + BN;
    int*            cnts     = bsum + CAP_L / TPB + 8;

    const int NB = (n + BN - 1) / BN;
    const int gn = (n + TPB - 1) / TPB;
    const int gs = (int)(((long)E + SCHUNK - 1) / SCHUNK);

    // ---- zero init ----
    (void)hipMemsetAsync(mark, 0, (size_t)n * sizeof(int), stream);
    (void)hipMemsetAsync(hist, 0, BN * sizeof(int), stream);
    (void)hipMemsetAsync(rcnt, 0, CAP_L * sizeof(int), stream);
    (void)hipMemsetAsync(cursor, 0, CAP_L * sizeof(int), stream);
    (void)hipMemsetAsync(cnts, 0, 16 * sizeof(int), stream);

    // ---- cone frontiers via edge scans (no CSR needed) ----
    seed_mark<<<1, 64, 0, stream>>>(idx, B, mark, L, rowOf, cnts);
    scanA_hist<<<1024, TPB, 0, stream>>>(dst, src, E, mark, L, rowOf, cnts, hist);
    snap<<<1, 64, 0, stream>>>(cnts, 1);                     // c4
    scan_expand<<<1024, TPB, 0, stream>>>(dst, src, E, mark, 2, 3, L, rowOf, cnts);
    snap<<<1, 64, 0, stream>>>(cnts, 2);                     // c3
    scan_expand<<<1024, TPB, 0, stream>>>(dst, src, E, mark, 3, 4, L, rowOf, cnts);
    snap<<<1, 64, 0, stream>>>(cnts, 3);                     // c2
    scan_filter<<<1024, TPB, 0, stream>>>(dst, src, E, mark, rowOf, fe_row, fe_src, rcnt, cnts);

    // ---- degrees -> dis (two-level u16 partition; no src payload) ----
    scan1024<<<1, BN, 0, stream>>>(hist, bucketOff, tails, E);
    scatter_u16<<<gs, STPB, 0, stream>>>(dst, tails, bdata, E);
    count_u16<<<NB, STPB, 0, stream>>>(bdata, bucketOff, dis, n);

    // ---- mini-CSR over filtered edges (dense rows = positions in L) ----
    scan_blocks<<<CAP_L / TPB, TPB, 0, stream>>>(rcnt, mrp, bsum, cnts);
    scan_bsum<<<1, TPB, 0, stream>>>(bsum, CAP_L / TPB);
    add_off<<<CAP_L / TPB, TPB, 0, stream>>>(mrp, bsum, cnts);
    fill_mcol<<<1024, TPB, 0, stream>>>(fe_row, fe_src, mrp, cursor, mcol, cnts);

    // ---- layers ----
    node_l1<<<gn, TPB, 0, stream>>>(x, W1, dis, hsA, n);
    pull_list<<<CAP_L / TPB, TPB, 0, stream>>>(L, cnts, 3, mrp, mcol, dis, hsA, b1, W2, hsB);
    pull_list<<<128, TPB, 0, stream>>>(L, cnts, 2, mrp, mcol, dis, hsB, b2, W3, hsA);
    pull_list<<<16, TPB, 0, stream>>>(L, cnts, 1, mrp, mcol, dis, hsA, b3, W4, hsB);
    pull_final<<<1, 64, 0, stream>>>(idx, B, rowOf, mrp, mcol, dis, hsB, b4, (float*)d_out);
}

// Round 10
// 736.856 us; speedup vs baseline: 3.9354x; 3.9354x over previous
//
#include <hip/hip_runtime.h>
#include <hip/hip_fp16.h>

#define TPB 256
#define BN 1024            // coarse buckets (10 low bits)
#define STPB 1024          // threads for scatter/count kernels
#define SCHUNK 16384       // edges per scatter block -> 611 blocks, 16 waves each
#define CAP_L 262144       // cone node list cap (|T2| ~ 85K mean)
#define CAP_E 1572864      // filtered edge cap (~850K mean)
#define SBUF 4096          // staged-append LDS buffer (expected ~80 appends/block)

typedef unsigned int uv4 __attribute__((ext_vector_type(4)));

// cnts slots: [0]=running list count, [1]=c4, [2]=c3, [3]=c2

// ---------------- seed: mark idx nodes (tag 1), append to L ----------------
__global__ void seed_mark(const int* __restrict__ idx, int B, int* __restrict__ mark,
                          int* __restrict__ L, int* __restrict__ rowOf, int* __restrict__ cnts) {
    int t = threadIdx.x;
    if (t < B) {
        int u = idx[t];
        if (atomicCAS(&mark[u], 0, 1) == 0) {
            int p = atomicAdd(&cnts[0], 1);
            L[p] = u; rowOf[u] = p;
        }
    }
}

// ------- expand scan: for edges with mark[dst] in (0,maxTag], CAS-mark src with newTag.
// New nodes staged in LDS; ONE global counter atomic per block (not per node).
// Optional: accumulate coarse degree histogram (hist != nullptr, scan A only).
__global__ void scan_mark(const int* __restrict__ dst, const int* __restrict__ src, int nE,
                          int* __restrict__ mark, int maxTag, int newTag,
                          int* __restrict__ L, int* __restrict__ rowOf, int* __restrict__ cnts,
                          int* __restrict__ hist) {
    __shared__ int lh[BN];
    __shared__ int buf[SBUF];
    __shared__ int bcnt, gbase;
    bool doHist = (hist != nullptr);
    if (doHist) for (int j = threadIdx.x; j < BN; j += blockDim.x) lh[j] = 0;
    if (threadIdx.x == 0) bcnt = 0;
    __syncthreads();
    int G = gridDim.x * blockDim.x;
    for (int e = blockIdx.x * blockDim.x + threadIdx.x; e < nE; e += G) {
        int d = dst[e];
        if (doHist) atomicAdd(&lh[d >> 10], 1);
        int m = mark[d];
        if (m > 0 && m <= maxTag) {
            int s = src[e];
            if (atomicCAS(&mark[s], 0, newTag) == 0) {
                int p = atomicAdd(&bcnt, 1);           // LDS atomic
                if (p < SBUF) buf[p] = s;
                else {                                  // overflow: direct append (P~0)
                    int gp = atomicAdd(&cnts[0], 1);
                    L[gp] = s; rowOf[s] = gp;
                }
            }
        }
    }
    __syncthreads();
    int m = bcnt < SBUF ? bcnt : SBUF;
    if (threadIdx.x == 0 && m > 0) gbase = atomicAdd(&cnts[0], m);
    __syncthreads();
    for (int k = threadIdx.x; k < m; k += blockDim.x) {
        int s = buf[k];
        int p = gbase + k;
        L[p] = s; rowOf[s] = p;
    }
    if (doHist) {
        for (int j = threadIdx.x; j < BN; j += blockDim.x)
            if (lh[j]) atomicAdd(&hist[j], lh[j]);
    }
}

__global__ void snap(int* __restrict__ cnts, int slot) {
    if (threadIdx.x == 0) cnts[slot] = cnts[0];
}

// ---------------- pass 1: row degree count over filtered edges (no global counter) ----
__global__ void count_rows(const int* __restrict__ dst, int nE, const int* __restrict__ mark,
                           const int* __restrict__ rowOf, int* __restrict__ rcnt) {
    int G = gridDim.x * blockDim.x;
    for (int e = blockIdx.x * blockDim.x + threadIdx.x; e < nE; e += G) {
        int d = dst[e];
        if (mark[d]) atomicAdd(&rcnt[rowOf[d]], 1);
    }
}

// ---------------- pass 2: direct scatter into mini-CSR ----------------
__global__ void fill_direct(const int* __restrict__ dst, const int* __restrict__ src, int nE,
                            const int* __restrict__ mark, const int* __restrict__ rowOf,
                            const int* __restrict__ mrp, int* __restrict__ cursor,
                            int* __restrict__ mcol) {
    int G = gridDim.x * blockDim.x;
    for (int e = blockIdx.x * blockDim.x + threadIdx.x; e < nE; e += G) {
        int d = dst[e];
        if (mark[d]) {
            int r = rowOf[d];
            int pos = atomicAdd(&cursor[r], 1);
            mcol[mrp[r] + pos] = src[e];
        }
    }
}

// ---------------- exclusive scan of 1024 bucket counts (degrees path) ----------------
__global__ void scan1024(const int* __restrict__ hist, int* __restrict__ bucketOff,
                         int* __restrict__ tails, int nE) {
    __shared__ int lds[BN];
    int t = threadIdx.x;
    int v = hist[t];
    lds[t] = v;
    __syncthreads();
    for (int off = 1; off < BN; off <<= 1) {
        int u = (t >= off) ? lds[t - off] : 0;
        __syncthreads();
        lds[t] += u;
        __syncthreads();
    }
    int excl = lds[t] - v;
    bucketOff[t] = excl;
    tails[t] = excl;
    if (t == BN - 1) bucketOff[BN] = lds[BN - 1];
}

// ---------------- scatter dstLow10 as u16 into coarse buckets (degrees only) ---------
__global__ __launch_bounds__(STPB) void scatter_u16(const int* __restrict__ dst,
                                                    int* __restrict__ tails,
                                                    unsigned short* __restrict__ bdata, int nE) {
    __shared__ int hist[BN];
    __shared__ int cbase[BN];
    int t = threadIdx.x;
    long base = (long)blockIdx.x * SCHUNK;
    int m = (int)(((long)nE - base < SCHUNK) ? (nE - base) : SCHUNK);
    hist[t] = 0;
    __syncthreads();
    for (int k = t; k < m; k += STPB) atomicAdd(&hist[dst[base + k] >> 10], 1);
    __syncthreads();
    int h = hist[t];
    cbase[t] = h ? atomicAdd(&tails[t], h) : 0;
    __syncthreads();
    hist[t] = 0;
    __syncthreads();
    for (int k = t; k < m; k += STPB) {
        int d = dst[base + k];
        int b = d >> 10;
        int r = atomicAdd(&hist[b], 1);
        bdata[cbase[b] + r] = (unsigned short)(d & (BN - 1));
    }
}

// ---------------- per-bucket degree count -> dis ----------------
__global__ __launch_bounds__(STPB) void count_u16(const unsigned short* __restrict__ bdata,
                                                  const int* __restrict__ bucketOff,
                                                  float* __restrict__ dis, int n) {
    __shared__ int cnt[BN];
    int b = blockIdx.x, t = threadIdx.x;
    cnt[t] = 0;
    __syncthreads();
    int e0 = bucketOff[b], e1 = bucketOff[b + 1];
    for (int k = e0 + t; k < e1; k += STPB) atomicAdd(&cnt[bdata[k]], 1);
    __syncthreads();
    int node = (b << 10) + t;
    if (node < n) dis[node] = rsqrtf((float)cnt[t] + 1.0f);
}

// ---------------- mini-CSR scan (rcnt[0..c2) -> mrp exclusive) ----------------
__global__ void scan_blocks(const int* __restrict__ rcnt, int* __restrict__ mrp,
                            int* __restrict__ bsum, const int* __restrict__ cnts) {
    __shared__ int lds[TPB];
    int c2 = cnts[3];
    int i = blockIdx.x * TPB + threadIdx.x;
    int v = (i < c2) ? rcnt[i] : 0;
    lds[threadIdx.x] = v;
    __syncthreads();
#pragma unroll
    for (int off = 1; off < TPB; off <<= 1) {
        int t = (threadIdx.x >= off) ? lds[threadIdx.x - off] : 0;
        __syncthreads();
        lds[threadIdx.x] += t;
        __syncthreads();
    }
    if (i < c2) mrp[i] = lds[threadIdx.x] - v;
    if (threadIdx.x == TPB - 1) bsum[blockIdx.x] = lds[TPB - 1];
}

__global__ void scan_bsum(int* __restrict__ bsum, int nb) {
    __shared__ int lds[TPB];
    int carry = 0;
    for (int base = 0; base < nb; base += TPB) {
        int i = base + threadIdx.x;
        int v = (i < nb) ? bsum[i] : 0;
        lds[threadIdx.x] = v;
        __syncthreads();
        for (int off = 1; off < TPB; off <<= 1) {
            int t = (threadIdx.x >= off) ? lds[threadIdx.x - off] : 0;
            __syncthreads();
            lds[threadIdx.x] += t;
            __syncthreads();
        }
        int incl = lds[threadIdx.x];
        if (i < nb) bsum[i] = carry + incl - v;
        carry += lds[TPB - 1];
        __syncthreads();
    }
    if (threadIdx.x == 0) bsum[nb] = carry;   // total = E2
}

__global__ void add_off(int* __restrict__ mrp, const int* __restrict__ bsum, int nb,
                        const int* __restrict__ cnts) {
    int i = blockIdx.x * TPB + threadIdx.x;
    int c2 = cnts[3];
    if (i < c2) mrp[i] += bsum[blockIdx.x];
    if (i == 0) mrp[c2] = bsum[nb];
}

union H8 { uv4 u; __half2 h2[4]; };

// ---------------- layer 1 (all nodes): hs = (x*W1)*dis  (fp16x8) ----------------
__global__ void node_l1(const float* __restrict__ x, const float* __restrict__ W1,
                        const float* __restrict__ dis, __half* __restrict__ hs, int n) {
    int i = blockIdx.x * blockDim.x + threadIdx.x;
    if (i >= n) return;
    float xd = x[i] * dis[i];
    float4 w0 = ((const float4*)W1)[0];
    float4 w1 = ((const float4*)W1)[1];
    H8 o;
    o.h2[0] = __floats2half2_rn(xd * w0.x, xd * w0.y);
    o.h2[1] = __floats2half2_rn(xd * w0.z, xd * w0.w);
    o.h2[2] = __floats2half2_rn(xd * w1.x, xd * w1.y);
    o.h2[3] = __floats2half2_rn(xd * w1.z, xd * w1.w);
    ((uv4*)hs)[i] = o.u;
}

// ---------------- fused pull + node transform over cone prefix [0, cnts[slot]) --------
__global__ void pull_list(const int* __restrict__ L, const int* __restrict__ cnts, int slot,
                          const int* __restrict__ mrp, const int* __restrict__ mcol,
                          const float* __restrict__ dis, const __half* __restrict__ hs_in,
                          const float* __restrict__ bias, const float* __restrict__ W,
                          __half* __restrict__ hs_out) {
    int tid = blockIdx.x * blockDim.x + threadIdx.x;
    if (tid >= cnts[slot]) return;
    int u = L[tid];
    const uv4* hv = (const uv4*)hs_in;
    H8 p; p.u = hv[u];                       // self term
    float2 a0 = __half22float2(p.h2[0]);
    float2 a1 = __half22float2(p.h2[1]);
    float2 a2 = __half22float2(p.h2[2]);
    float2 a3 = __half22float2(p.h2[3]);
    int s = mrp[tid], e = mrp[tid + 1];
    for (int k = s; k < e; ++k) {
        H8 q; q.u = hv[mcol[k]];
        float2 b0 = __half22float2(q.h2[0]);
        float2 b1 = __half22float2(q.h2[1]);
        float2 b2 = __half22float2(q.h2[2]);
        float2 b3 = __half22float2(q.h2[3]);
        a0.x += b0.x; a0.y += b0.y; a1.x += b1.x; a1.y += b1.y;
        a2.x += b2.x; a2.y += b2.y; a3.x += b3.x; a3.y += b3.y;
    }
    float d = dis[u];
    float t[8] = {a0.x * d, a0.y * d, a1.x * d, a1.y * d,
                  a2.x * d, a2.y * d, a3.x * d, a3.y * d};
#pragma unroll
    for (int k = 0; k < 8; ++k) {
        float v = t[k] + bias[k];
        t[k] = v > 0.0f ? v : 0.0f;
    }
    float h[8];
#pragma unroll
    for (int j = 0; j < 8; ++j) {
        float acc = 0.0f;
#pragma unroll
        for (int k = 0; k < 8; ++k) acc += t[k] * W[k * 8 + j];
        h[j] = acc * d;
    }
    H8 o;
    o.h2[0] = __floats2half2_rn(h[0], h[1]);
    o.h2[1] = __floats2half2_rn(h[2], h[3]);
    o.h2[2] = __floats2half2_rn(h[4], h[5]);
    o.h2[3] = __floats2half2_rn(h[6], h[7]);
    ((uv4*)hs_out)[u] = o.u;
}

// ---------------- final: out[t][:] = dis*(sum+self) + b4, for the idx nodes ------
__global__ void pull_final(const int* __restrict__ idx, int B, const int* __restrict__ rowOf,
                           const int* __restrict__ mrp, const int* __restrict__ mcol,
                           const float* __restrict__ dis, const __half* __restrict__ hs_in,
                           const float* __restrict__ b4, float* __restrict__ out) {
    int t = blockIdx.x * blockDim.x + threadIdx.x;
    if (t >= B) return;
    int u = idx[t];
    int rr = rowOf[u];
    const uv4* hv = (const uv4*)hs_in;
    H8 p; p.u = hv[u];
    float2 a0 = __half22float2(p.h2[0]);
    float2 a1 = __half22float2(p.h2[1]);
    float2 a2 = __half22float2(p.h2[2]);
    float2 a3 = __half22float2(p.h2[3]);
    int s = mrp[rr], e = mrp[rr + 1];
    for (int k = s; k < e; ++k) {
        H8 q; q.u = hv[mcol[k]];
        float2 b0 = __half22float2(q.h2[0]);
        float2 b1 = __half22float2(q.h2[1]);
        float2 b2 = __half22float2(q.h2[2]);
        float2 b3 = __half22float2(q.h2[3]);
        a0.x += b0.x; a0.y += b0.y; a1.x += b1.x; a1.y += b1.y;
        a2.x += b2.x; a2.y += b2.y; a3.x += b3.x; a3.y += b3.y;
    }
    float d = dis[u];
    float* op = out + (size_t)t * 8;
    op[0] = a0.x * d + b4[0]; op[1] = a0.y * d + b4[1];
    op[2] = a1.x * d + b4[2]; op[3] = a1.y * d + b4[3];
    op[4] = a2.x * d + b4[4]; op[5] = a2.y * d + b4[5];
    op[6] = a3.x * d + b4[6]; op[7] = a3.y * d + b4[7];
}

extern "C" void kernel_launch(void* const* d_in, const int* in_sizes, int n_in,
                              void* d_out, int out_size, void* d_ws, size_t ws_size,
                              hipStream_t stream) {
    const float* x   = (const float*)d_in[0];
    const int*   ei  = (const int*)d_in[1];
    const int*   idx = (const int*)d_in[2];
    const float* W1  = (const float*)d_in[3];
    const float* b1  = (const float*)d_in[4];
    const float* W2  = (const float*)d_in[5];
    const float* b2  = (const float*)d_in[6];
    const float* W3  = (const float*)d_in[7];
    const float* b3  = (const float*)d_in[8];
    const float* W4  = (const float*)d_in[9];
    const float* b4  = (const float*)d_in[10];

    const int n = in_sizes[0];      // 1,000,000 nodes (n <= 2^20 for bucketing)
    const int E = in_sizes[1] / 2;  // 10,000,000 edges
    const int B = in_sizes[2];      // 64 graphs

    const int* src = ei;
    const int* dst = ei + E;

    // workspace (int elements):
    size_t o_mark   = 0;
    size_t o_rowOf  = o_mark   + (size_t)n;
    size_t o_dis    = o_rowOf  + (size_t)n;
    size_t o_hsA    = o_dis    + (size_t)n;
    size_t o_hsB    = o_hsA    + (size_t)n * 4;
    size_t o_L      = o_hsB    + (size_t)n * 4;
    size_t o_mrp    = o_L      + CAP_L;
    size_t o_rcnt   = o_mrp    + CAP_L + 8;
    size_t o_cursor = o_rcnt   + CAP_L;
    size_t o_mcol   = o_cursor + CAP_L;
    size_t o_u16    = o_mcol   + CAP_E;
    size_t o_small  = o_u16    + (size_t)E / 2 + 4;

    int*            mark     = (int*)d_ws + o_mark;
    int*            rowOf    = (int*)d_ws + o_rowOf;
    float*          dis      = (float*)d_ws + o_dis;
    __half*         hsA      = (__half*)((int*)d_ws + o_hsA);
    __half*         hsB      = (__half*)((int*)d_ws + o_hsB);
    int*            L        = (int*)d_ws + o_L;
    int*            mrp      = (int*)d_ws + o_mrp;
    int*            rcnt     = (int*)d_ws + o_rcnt;
    int*            cursor   = (int*)d_ws + o_cursor;
    int*            mcol     = (int*)d_ws + o_mcol;
    unsigned short* bdata    = (unsigned short*)((int*)d_ws + o_u16);
    int*            hist     = (int*)d_ws + o_small;
    int*            bucketOff= hist + BN;
    int*            tails    = bucketOff + BN + 8;
    int*            bsum     = tails + BN;
    int*            cnts     = bsum + CAP_L / TPB + 8;

    const int NB = (n + BN - 1) / BN;
    const int gn = (n + TPB - 1) / TPB;
    const int gs = (int)(((long)E + SCHUNK - 1) / SCHUNK);
    const int nb = CAP_L / TPB;

    // ---- zero init ----
    (void)hipMemsetAsync(mark, 0, (size_t)n * sizeof(int), stream);
    (void)hipMemsetAsync(hist, 0, BN * sizeof(int), stream);
    (void)hipMemsetAsync(rcnt, 0, CAP_L * sizeof(int), stream);
    (void)hipMemsetAsync(cursor, 0, CAP_L * sizeof(int), stream);
    (void)hipMemsetAsync(cnts, 0, 16 * sizeof(int), stream);

    // ---- cone frontiers via edge scans (block-staged appends) ----
    seed_mark<<<1, 64, 0, stream>>>(idx, B, mark, L, rowOf, cnts);
    scan_mark<<<1024, TPB, 0, stream>>>(dst, src, E, mark, 1, 2, L, rowOf, cnts, hist);
    snap<<<1, 64, 0, stream>>>(cnts, 1);                     // c4
    scan_mark<<<1024, TPB, 0, stream>>>(dst, src, E, mark, 2, 3, L, rowOf, cnts, nullptr);
    snap<<<1, 64, 0, stream>>>(cnts, 2);                     // c3
    scan_mark<<<1024, TPB, 0, stream>>>(dst, src, E, mark, 3, 4, L, rowOf, cnts, nullptr);
    snap<<<1, 64, 0, stream>>>(cnts, 3);                     // c2

    // ---- mini-CSR over filtered edges: count -> scan -> direct fill ----
    count_rows<<<1024, TPB, 0, stream>>>(dst, E, mark, rowOf, rcnt);
    scan_blocks<<<nb, TPB, 0, stream>>>(rcnt, mrp, bsum, cnts);
    scan_bsum<<<1, TPB, 0, stream>>>(bsum, nb);
    add_off<<<nb, TPB, 0, stream>>>(mrp, bsum, nb, cnts);
    fill_direct<<<1024, TPB, 0, stream>>>(dst, src, E, mark, rowOf, mrp, cursor, mcol);

    // ---- degrees -> dis (two-level u16 partition) ----
    scan1024<<<1, BN, 0, stream>>>(hist, bucketOff, tails, E);
    scatter_u16<<<gs, STPB, 0, stream>>>(dst, tails, bdata, E);
    count_u16<<<NB, STPB, 0, stream>>>(bdata, bucketOff, dis, n);

    // ---- layers ----
    node_l1<<<gn, TPB, 0, stream>>>(x, W1, dis, hsA, n);
    pull_list<<<nb, TPB, 0, stream>>>(L, cnts, 3, mrp, mcol, dis, hsA, b1, W2, hsB);
    pull_list<<<128, TPB, 0, stream>>>(L, cnts, 2, mrp, mcol, dis, hsB, b2, W3, hsA);
    pull_list<<<16, TPB, 0, stream>>>(L, cnts, 1, mrp, mcol, dis, hsA, b3, W4, hsB);
    pull_final<<<1, 64, 0, stream>>>(idx, B, rowOf, mrp, mcol, dis, hsB, b4, (float*)d_out);
}

// Round 11
// 661.088 us; speedup vs baseline: 4.3864x; 1.1146x over previous
//
#include <hip/hip_runtime.h>
#include <hip/hip_fp16.h>

#define TPB 256
#define BN 1024            // nodes per bucket (10 low bits)
#define STPB 1024          // threads for scatter32
#define SCHUNK 32768       // edges per scatter block -> 306 blocks x 16 waves
#define CAP_L 262144       // cone row cap (|T2| ~ 85K mean)
#define CAP_E 1572864      // filtered edge cap (~850K mean)

typedef unsigned int uv4 __attribute__((ext_vector_type(4)));

// ---------------- coarse histogram of dst >> 10 ----------------
__global__ void hist_buckets(const int* __restrict__ dst, int* __restrict__ hist, int nE) {
    __shared__ int lh[BN];
    for (int j = threadIdx.x; j < BN; j += blockDim.x) lh[j] = 0;
    __syncthreads();
    int G = gridDim.x * blockDim.x;
    for (int e = blockIdx.x * blockDim.x + threadIdx.x; e < nE; e += G)
        atomicAdd(&lh[__builtin_nontemporal_load(&dst[e]) >> 10], 1);
    __syncthreads();
    for (int j = threadIdx.x; j < BN; j += blockDim.x)
        if (lh[j]) atomicAdd(&hist[j], lh[j]);
}

// ---------------- exclusive scan of 1024 bucket counts ----------------
__global__ void scan1024(const int* __restrict__ hist, int* __restrict__ bucketOff,
                         int* __restrict__ tails) {
    __shared__ int lds[BN];
    int t = threadIdx.x;
    int v = hist[t];
    lds[t] = v;
    __syncthreads();
    for (int off = 1; off < BN; off <<= 1) {
        int u = (t >= off) ? lds[t - off] : 0;
        __syncthreads();
        lds[t] += u;
        __syncthreads();
    }
    int excl = lds[t] - v;
    bucketOff[t] = excl;
    tails[t] = excl;
    if (t == BN - 1) bucketOff[BN] = lds[BN - 1];   // == nE
}

// ---------------- partition edges by dst bucket: payload (dstLow10<<20)|src ----------
__global__ __launch_bounds__(STPB) void scatter32(const int* __restrict__ dst,
                                                  const int* __restrict__ src,
                                                  int* __restrict__ tails,
                                                  unsigned* __restrict__ bdata, int nE) {
    __shared__ int hist[BN];
    __shared__ int cbase[BN];
    int t = threadIdx.x;
    long base = (long)blockIdx.x * SCHUNK;
    int m = (int)(((long)nE - base < SCHUNK) ? (nE - base) : SCHUNK);
    hist[t] = 0;
    __syncthreads();
    for (int k = t; k < m; k += STPB)
        atomicAdd(&hist[__builtin_nontemporal_load(&dst[base + k]) >> 10], 1);
    __syncthreads();
    int h = hist[t];
    cbase[t] = h ? atomicAdd(&tails[t], h) : 0;
    __syncthreads();
    hist[t] = 0;
    __syncthreads();
    for (int k = t; k < m; k += STPB) {
        int d = dst[base + k];
        int b = d >> 10;
        int r = atomicAdd(&hist[b], 1);
        bdata[cbase[b] + r] = ((unsigned)(d & (BN - 1)) << 20) | (unsigned)src[base + k];
    }
}

// ---------------- seed: mark idx nodes (tag 1) ----------------
__global__ void seed_mark(const int* __restrict__ idx, int B, int* __restrict__ mark) {
    int t = threadIdx.x;
    if (t < B) mark[idx[t]] = 1;
}

// ------- expansion: one block per bucket; LDS mark snapshot; sequential edge stream ---
__global__ void expand_b(const unsigned* __restrict__ bdata, const int* __restrict__ bucketOff,
                         int* __restrict__ mark, int maxTag, int newTag, int n) {
    __shared__ int lm[BN];
    int b = blockIdx.x, t = threadIdx.x;
    int base = b << 10;
    for (int j = t; j < BN; j += TPB) lm[j] = (base + j < n) ? mark[base + j] : 0;
    __syncthreads();
    int e0 = bucketOff[b], e1 = bucketOff[b + 1];
    for (int k = e0 + t; k < e1; k += TPB) {
        unsigned p = __builtin_nontemporal_load(&bdata[k]);
        int m = lm[p >> 20];
        if (m > 0 && m <= maxTag) {
            int s = (int)(p & 0xFFFFFu);
            if (mark[s] == 0) atomicCAS(&mark[s], 0, newTag);   // rare (~hits only)
        }
    }
}

// ---------------- degrees -> dis, per bucket ----------------
__global__ void count_dis(const unsigned* __restrict__ bdata, const int* __restrict__ bucketOff,
                          float* __restrict__ dis, int n) {
    __shared__ int cnt[BN];
    int b = blockIdx.x, t = threadIdx.x;
    for (int j = t; j < BN; j += TPB) cnt[j] = 0;
    __syncthreads();
    int e0 = bucketOff[b], e1 = bucketOff[b + 1];
    for (int k = e0 + t; k < e1; k += TPB)
        atomicAdd(&cnt[__builtin_nontemporal_load(&bdata[k]) >> 20], 1);
    __syncthreads();
    int base = b << 10;
    for (int j = t; j < BN; j += TPB) {
        int node = base + j;
        if (node < n) dis[node] = rsqrtf((float)cnt[j] + 1.0f);
    }
}

// ---------------- global rank scan over mark (dense rows in node-id order) ------------
__global__ void rank_blocks(const int* __restrict__ mark, int* __restrict__ rank,
                            int* __restrict__ bsum, int n) {
    __shared__ int lds[TPB];
    int i = blockIdx.x * TPB + threadIdx.x;
    int v = (i < n && mark[i] != 0) ? 1 : 0;
    lds[threadIdx.x] = v;
    __syncthreads();
#pragma unroll
    for (int off = 1; off < TPB; off <<= 1) {
        int t = (threadIdx.x >= off) ? lds[threadIdx.x - off] : 0;
        __syncthreads();
        lds[threadIdx.x] += t;
        __syncthreads();
    }
    if (i < n) rank[i] = lds[threadIdx.x] - v;
    if (threadIdx.x == TPB - 1) bsum[blockIdx.x] = lds[TPB - 1];
}

__global__ void bsum_scan(int* __restrict__ bsum, int nb, int* __restrict__ total) {
    __shared__ int lds[TPB];
    int carry = 0;
    for (int base = 0; base < nb; base += TPB) {
        int i = base + threadIdx.x;
        int v = (i < nb) ? bsum[i] : 0;
        lds[threadIdx.x] = v;
        __syncthreads();
        for (int off = 1; off < TPB; off <<= 1) {
            int t = (threadIdx.x >= off) ? lds[threadIdx.x - off] : 0;
            __syncthreads();
            lds[threadIdx.x] += t;
            __syncthreads();
        }
        int incl = lds[threadIdx.x];
        if (i < nb) bsum[i] = carry + incl - v;
        carry += lds[TPB - 1];
        __syncthreads();
    }
    if (threadIdx.x == 0) *total = carry;
}

__global__ void rank_add(int* __restrict__ rank, const int* __restrict__ bsum,
                         const int* __restrict__ mark, int* __restrict__ L,
                         int* __restrict__ T, int n) {
    int i = blockIdx.x * TPB + threadIdx.x;
    if (i >= n) return;
    int r = rank[i] + bsum[blockIdx.x];
    rank[i] = r;
    int m = mark[i];
    if (m) { L[r] = i; T[r] = m; }
}

// ---------------- per-bucket row degree count (marked dst only) ----------------
__global__ void count_rows_b(const unsigned* __restrict__ bdata, const int* __restrict__ bucketOff,
                             const int* __restrict__ mark, const int* __restrict__ rank,
                             int* __restrict__ rcnt, int n) {
    __shared__ int lm[BN];
    __shared__ int cnt[BN];
    int b = blockIdx.x, t = threadIdx.x;
    int base = b << 10;
    for (int j = t; j < BN; j += TPB) {
        lm[j] = (base + j < n) ? mark[base + j] : 0;
        cnt[j] = 0;
    }
    __syncthreads();
    int e0 = bucketOff[b], e1 = bucketOff[b + 1];
    for (int k = e0 + t; k < e1; k += TPB) {
        unsigned p = __builtin_nontemporal_load(&bdata[k]);
        int j = p >> 20;
        if (lm[j]) atomicAdd(&cnt[j], 1);
    }
    __syncthreads();
    for (int j = t; j < BN; j += TPB) {
        int node = base + j;
        if (node < n && lm[j]) rcnt[rank[node]] = cnt[j];
    }
}

// ---------------- mrp scan over rcnt[0..c2) ----------------
__global__ void mrp_blocks(const int* __restrict__ rcnt, int* __restrict__ mrp,
                           int* __restrict__ bsum, const int* __restrict__ cnts) {
    __shared__ int lds[TPB];
    int c2 = cnts[0];
    int i = blockIdx.x * TPB + threadIdx.x;
    int v = (i < c2) ? rcnt[i] : 0;
    lds[threadIdx.x] = v;
    __syncthreads();
#pragma unroll
    for (int off = 1; off < TPB; off <<= 1) {
        int t = (threadIdx.x >= off) ? lds[threadIdx.x - off] : 0;
        __syncthreads();
        lds[threadIdx.x] += t;
        __syncthreads();
    }
    if (i < c2) mrp[i] = lds[threadIdx.x] - v;
    if (threadIdx.x == TPB - 1) bsum[blockIdx.x] = lds[TPB - 1];
}

__global__ void mrp_add(int* __restrict__ mrp, const int* __restrict__ bsum, int nb,
                        const int* __restrict__ cnts) {
    int c2 = cnts[0];
    int i = blockIdx.x * TPB + threadIdx.x;
    if (i < c2) mrp[i] += bsum[blockIdx.x];
    if (i == 0) mrp[c2] = bsum[nb];     // total filtered edges
}

// ---------------- per-bucket fill: mcol writes land in a ~3 KB contiguous region ------
__global__ void fill_b(const unsigned* __restrict__ bdata, const int* __restrict__ bucketOff,
                       const int* __restrict__ mark, const int* __restrict__ rank,
                       const int* __restrict__ mrp, int* __restrict__ mcol, int n) {
    __shared__ int lm[BN];
    __shared__ int cur[BN];
    int b = blockIdx.x, t = threadIdx.x;
    int base = b << 10;
    for (int j = t; j < BN; j += TPB) {
        int node = base + j;
        int m = (node < n) ? mark[node] : 0;
        lm[j] = m;
        cur[j] = m ? mrp[rank[node]] : 0;   // rank contiguous for marked -> coalesced mrp
    }
    __syncthreads();
    int e0 = bucketOff[b], e1 = bucketOff[b + 1];
    for (int k = e0 + t; k < e1; k += TPB) {
        unsigned p = __builtin_nontemporal_load(&bdata[k]);
        int j = p >> 20;
        if (lm[j]) {
            int pos = atomicAdd(&cur[j], 1);
            mcol[pos] = (int)(p & 0xFFFFFu);
        }
    }
}

union H8 { uv4 u; __half2 h2[4]; };

// ---------------- layer 1 (all nodes): hs = (x*W1)*dis  (fp16x8) ----------------
__global__ void node_l1(const float* __restrict__ x, const float* __restrict__ W1,
                        const float* __restrict__ dis, __half* __restrict__ hs, int n) {
    int i = blockIdx.x * blockDim.x + threadIdx.x;
    if (i >= n) return;
    float xd = x[i] * dis[i];
    float4 w0 = ((const float4*)W1)[0];
    float4 w1 = ((const float4*)W1)[1];
    H8 o;
    o.h2[0] = __floats2half2_rn(xd * w0.x, xd * w0.y);
    o.h2[1] = __floats2half2_rn(xd * w0.z, xd * w0.w);
    o.h2[2] = __floats2half2_rn(xd * w1.x, xd * w1.y);
    o.h2[3] = __floats2half2_rn(xd * w1.z, xd * w1.w);
    ((uv4*)hs)[i] = o.u;
}

// ---------------- fused pull + node transform over rows with tag <= tagMax ------------
__global__ void pull_tag(const int* __restrict__ L, const int* __restrict__ T,
                         const int* __restrict__ cnts, int tagMax,
                         const int* __restrict__ mrp, const int* __restrict__ mcol,
                         const float* __restrict__ dis, const __half* __restrict__ hs_in,
                         const float* __restrict__ bias, const float* __restrict__ W,
                         __half* __restrict__ hs_out) {
    int r = blockIdx.x * blockDim.x + threadIdx.x;
    if (r >= cnts[0]) return;
    if (T[r] > tagMax) return;
    int u = L[r];
    const uv4* hv = (const uv4*)hs_in;
    H8 p; p.u = hv[u];                       // self term
    float2 a0 = __half22float2(p.h2[0]);
    float2 a1 = __half22float2(p.h2[1]);
    float2 a2 = __half22float2(p.h2[2]);
    float2 a3 = __half22float2(p.h2[3]);
    int s = mrp[r], e = mrp[r + 1];
    for (int k = s; k < e; ++k) {
        H8 q; q.u = hv[mcol[k]];
        float2 b0 = __half22float2(q.h2[0]);
        float2 b1 = __half22float2(q.h2[1]);
        float2 b2 = __half22float2(q.h2[2]);
        float2 b3 = __half22float2(q.h2[3]);
        a0.x += b0.x; a0.y += b0.y; a1.x += b1.x; a1.y += b1.y;
        a2.x += b2.x; a2.y += b2.y; a3.x += b3.x; a3.y += b3.y;
    }
    float d = dis[u];
    float t[8] = {a0.x * d, a0.y * d, a1.x * d, a1.y * d,
                  a2.x * d, a2.y * d, a3.x * d, a3.y * d};
#pragma unroll
    for (int k = 0; k < 8; ++k) {
        float v = t[k] + bias[k];
        t[k] = v > 0.0f ? v : 0.0f;
    }
    float h[8];
#pragma unroll
    for (int j = 0; j < 8; ++j) {
        float acc = 0.0f;
#pragma unroll
        for (int k = 0; k < 8; ++k) acc += t[k] * W[k * 8 + j];
        h[j] = acc * d;
    }
    H8 o;
    o.h2[0] = __floats2half2_rn(h[0], h[1]);
    o.h2[1] = __floats2half2_rn(h[2], h[3]);
    o.h2[2] = __floats2half2_rn(h[4], h[5]);
    o.h2[3] = __floats2half2_rn(h[6], h[7]);
    ((uv4*)hs_out)[u] = o.u;
}

// ---------------- final: out[t][:] = dis*(sum+self) + b4, for the idx nodes ------
__global__ void pull_final(const int* __restrict__ idx, int B, const int* __restrict__ rank,
                           const int* __restrict__ mrp, const int* __restrict__ mcol,
                           const float* __restrict__ dis, const __half* __restrict__ hs_in,
                           const float* __restrict__ b4, float* __restrict__ out) {
    int t = blockIdx.x * blockDim.x + threadIdx.x;
    if (t >= B) return;
    int u = idx[t];
    int rr = rank[u];
    const uv4* hv = (const uv4*)hs_in;
    H8 p; p.u = hv[u];
    float2 a0 = __half22float2(p.h2[0]);
    float2 a1 = __half22float2(p.h2[1]);
    float2 a2 = __half22float2(p.h2[2]);
    float2 a3 = __half22float2(p.h2[3]);
    int s = mrp[rr], e = mrp[rr + 1];
    for (int k = s; k < e; ++k) {
        H8 q; q.u = hv[mcol[k]];
        float2 b0 = __half22float2(q.h2[0]);
        float2 b1 = __half22float2(q.h2[1]);
        float2 b2 = __half22float2(q.h2[2]);
        float2 b3 = __half22float2(q.h2[3]);
        a0.x += b0.x; a0.y += b0.y; a1.x += b1.x; a1.y += b1.y;
        a2.x += b2.x; a2.y += b2.y; a3.x += b3.x; a3.y += b3.y;
    }
    float d = dis[u];
    float* op = out + (size_t)t * 8;
    op[0] = a0.x * d + b4[0]; op[1] = a0.y * d + b4[1];
    op[2] = a1.x * d + b4[2]; op[3] = a1.y * d + b4[3];
    op[4] = a2.x * d + b4[4]; op[5] = a2.y * d + b4[5];
    op[6] = a3.x * d + b4[6]; op[7] = a3.y * d + b4[7];
}

extern "C" void kernel_launch(void* const* d_in, const int* in_sizes, int n_in,
                              void* d_out, int out_size, void* d_ws, size_t ws_size,
                              hipStream_t stream) {
    const float* x   = (const float*)d_in[0];
    const int*   ei  = (const int*)d_in[1];
    const int*   idx = (const int*)d_in[2];
    const float* W1  = (const float*)d_in[3];
    const float* b1  = (const float*)d_in[4];
    const float* W2  = (const float*)d_in[5];
    const float* b2  = (const float*)d_in[6];
    const float* W3  = (const float*)d_in[7];
    const float* b3  = (const float*)d_in[8];
    const float* W4  = (const float*)d_in[9];
    const float* b4  = (const float*)d_in[10];

    const int n = in_sizes[0];      // 1,000,000 nodes (n <= 2^20 for packing)
    const int E = in_sizes[1] / 2;  // 10,000,000 edges
    const int B = in_sizes[2];      // 64 graphs

    const int* src = ei;
    const int* dst = ei + E;

    // workspace (int elements):
    size_t o_mark  = 0;
    size_t o_rank  = o_mark  + (size_t)n;
    size_t o_dis   = o_rank  + (size_t)n;
    size_t o_hsA   = o_dis   + (size_t)n;
    size_t o_hsB   = o_hsA   + (size_t)n * 4;
    size_t o_L     = o_hsB   + (size_t)n * 4;
    size_t o_T     = o_L     + CAP_L;
    size_t o_rcnt  = o_T     + CAP_L;
    size_t o_mrp   = o_rcnt  + CAP_L;
    size_t o_mcol  = o_mrp   + CAP_L + 8;
    size_t o_bd    = o_mcol  + CAP_E;
    size_t o_small = o_bd    + (size_t)E;

    int*      mark      = (int*)d_ws + o_mark;
    int*      rank      = (int*)d_ws + o_rank;
    float*    dis       = (float*)d_ws + o_dis;
    __half*   hsA       = (__half*)((int*)d_ws + o_hsA);
    __half*   hsB       = (__half*)((int*)d_ws + o_hsB);
    int*      L         = (int*)d_ws + o_L;
    int*      T         = (int*)d_ws + o_T;
    int*      rcnt      = (int*)d_ws + o_rcnt;
    int*      mrp       = (int*)d_ws + o_mrp;
    int*      mcol      = (int*)d_ws + o_mcol;
    unsigned* bdata     = (unsigned*)((int*)d_ws + o_bd);
    int*      hist      = (int*)d_ws + o_small;
    int*      bucketOff = hist + BN;
    int*      tails     = bucketOff + BN + 8;
    int*      bsum1     = tails + BN;            // rank-scan block sums (<= 4096+8)
    int*      bsum2     = bsum1 + 4096 + 8;      // mrp-scan block sums (1024+8)
    int*      cnts      = bsum2 + 1024 + 8;      // [0] = c2

    const int NB   = (n + BN - 1) / BN;          // 977 buckets
    const int gnN  = (n + TPB - 1) / TPB;        // 3907
    const int gs   = (int)(((long)E + SCHUNK - 1) / SCHUNK);   // 306
    const int nb2  = CAP_L / TPB;                // 1024

    // ---- zero init ----
    (void)hipMemsetAsync(mark, 0, (size_t)n * sizeof(int), stream);
    (void)hipMemsetAsync(hist, 0, BN * sizeof(int), stream);
    (void)hipMemsetAsync(cnts, 0, 8 * sizeof(int), stream);

    // ---- bucket partition of the edge list (the one expensive pass) ----
    hist_buckets<<<1024, TPB, 0, stream>>>(dst, hist, E);
    scan1024<<<1, BN, 0, stream>>>(hist, bucketOff, tails);
    scatter32<<<gs, STPB, 0, stream>>>(dst, src, tails, bdata, E);

    // ---- cone expansion: sequential bucket scans, LDS marks ----
    seed_mark<<<1, 64, 0, stream>>>(idx, B, mark);
    expand_b<<<NB, TPB, 0, stream>>>(bdata, bucketOff, mark, 1, 2, n);   // T4
    expand_b<<<NB, TPB, 0, stream>>>(bdata, bucketOff, mark, 2, 3, n);   // T3
    expand_b<<<NB, TPB, 0, stream>>>(bdata, bucketOff, mark, 3, 4, n);   // T2

    // ---- degrees -> dis ----
    count_dis<<<NB, TPB, 0, stream>>>(bdata, bucketOff, dis, n);

    // ---- dense rows in node-id order: rank scan ----
    rank_blocks<<<gnN, TPB, 0, stream>>>(mark, rank, bsum1, n);
    bsum_scan<<<1, TPB, 0, stream>>>(bsum1, gnN, &cnts[0]);
    rank_add<<<gnN, TPB, 0, stream>>>(rank, bsum1, mark, L, T, n);

    // ---- mini-CSR: count -> scan -> fill (all bucket-sequential) ----
    count_rows_b<<<NB, TPB, 0, stream>>>(bdata, bucketOff, mark, rank, rcnt, n);
    mrp_blocks<<<nb2, TPB, 0, stream>>>(rcnt, mrp, bsum2, cnts);
    bsum_scan<<<1, TPB, 0, stream>>>(bsum2, nb2, &bsum2[nb2]);
    mrp_add<<<nb2, TPB, 0, stream>>>(mrp, bsum2, nb2, cnts);
    fill_b<<<NB, TPB, 0, stream>>>(bdata, bucketOff, mark, rank, mrp, mcol, n);

    // ---- layers ----
    node_l1<<<gnN, TPB, 0, stream>>>(x, W1, dis, hsA, n);
    pull_tag<<<nb2, TPB, 0, stream>>>(L, T, cnts, 4, mrp, mcol, dis, hsA, b1, W2, hsB);
    pull_tag<<<nb2, TPB, 0, stream>>>(L, T, cnts, 3, mrp, mcol, dis, hsB, b2, W3, hsA);
    pull_tag<<<nb2, TPB, 0, stream>>>(L, T, cnts, 2, mrp, mcol, dis, hsA, b3, W4, hsB);
    pull_final<<<1, 64, 0, stream>>>(idx, B, rank, mrp, mcol, dis, hsB, b4, (float*)d_out);
}

// Round 12
// 605.349 us; speedup vs baseline: 4.7903x; 1.0921x over previous
//
#include <hip/hip_runtime.h>
#include <hip/hip_fp16.h>

#define TPB 256
#define BTPB 512           // threads for per-bucket kernels
#define NBK 256            // buckets (dst >> 12)
#define BNODES 4096        // nodes per bucket
#define CH 10240           // edges per scatter_sort chunk (LDS-staged)
#define CAP_L 262144       // cone row cap (|T2| ~ 85K mean)
#define CAP_E 1572864      // filtered edge cap (~850K mean)

typedef unsigned int uv4 __attribute__((ext_vector_type(4)));

// ---------------- coarse histogram of dst >> 12 ----------------
__global__ void hist_buckets(const int* __restrict__ dst, int* __restrict__ hist, int nE) {
    __shared__ int lh[NBK];
    if (threadIdx.x < NBK) lh[threadIdx.x] = 0;
    __syncthreads();
    int G = gridDim.x * blockDim.x;
    for (int e = blockIdx.x * blockDim.x + threadIdx.x; e < nE; e += G)
        atomicAdd(&lh[__builtin_nontemporal_load(&dst[e]) >> 12], 1);
    __syncthreads();
    if (threadIdx.x < NBK && lh[threadIdx.x]) atomicAdd(&hist[threadIdx.x], lh[threadIdx.x]);
}

// ---------------- exclusive scan of 256 bucket counts ----------------
__global__ void scan256(const int* __restrict__ hist, int* __restrict__ bucketOff,
                        int* __restrict__ tails) {
    __shared__ int lds[NBK];
    int t = threadIdx.x;
    int v = hist[t];
    lds[t] = v;
    __syncthreads();
    for (int off = 1; off < NBK; off <<= 1) {
        int u = (t >= off) ? lds[t - off] : 0;
        __syncthreads();
        lds[t] += u;
        __syncthreads();
    }
    int excl = lds[t] - v;
    bucketOff[t] = excl;
    tails[t] = excl;
    if (t == NBK - 1) bucketOff[NBK] = lds[NBK - 1];   // == nE
}

// ------- partition edges by dst bucket; LDS counting sort per chunk, burst flush -------
// payload: (dstLow12 << 20) | src  (exactly 32 bits; requires n <= 2^20)
__global__ __launch_bounds__(TPB) void scatter_sort(const int* __restrict__ dst,
                                                    const int* __restrict__ src,
                                                    int* __restrict__ tails,
                                                    unsigned* __restrict__ bdata, int nE) {
    __shared__ unsigned      stage[CH];      // 40 KB
    __shared__ unsigned char bkt[CH];        // 10 KB
    __shared__ int cnt[NBK], sstart[NBK], cur[NBK], cbase[NBK];   // 4 KB
    int t = threadIdx.x;
    long base = (long)blockIdx.x * CH;
    int m = (int)(((long)nE - base < CH) ? (nE - base) : CH);
    cnt[t] = 0;
    __syncthreads();
    // pass 1: count
    for (int k = t; k < m; k += TPB)
        atomicAdd(&cnt[__builtin_nontemporal_load(&dst[base + k]) >> 12], 1);
    __syncthreads();
    // exclusive scan cnt -> sstart
    {
        int v = cnt[t];
        int acc = v;
        __shared__ int lds[NBK];
        lds[t] = acc;
        __syncthreads();
        for (int off = 1; off < NBK; off <<= 1) {
            int u = (t >= off) ? lds[t - off] : 0;
            __syncthreads();
            lds[t] += u;
            __syncthreads();
        }
        sstart[t] = lds[t] - v;
        cur[t] = lds[t] - v;
    }
    __syncthreads();
    // pass 2: place into LDS, sorted by bucket
    for (int k = t; k < m; k += TPB) {
        int d = dst[base + k];
        int s = src[base + k];
        int b = d >> 12;
        int pos = atomicAdd(&cur[b], 1);
        stage[pos] = ((unsigned)(d & 4095) << 20) | (unsigned)s;
        bkt[pos] = (unsigned char)b;
    }
    __syncthreads();
    // reserve global runs
    cbase[t] = cnt[t] ? atomicAdd(&tails[t], cnt[t]) : 0;
    __syncthreads();
    // burst flush: consecutive threads -> consecutive dests; lines filled completely
    for (int k = t; k < m; k += TPB) {
        int b = bkt[k];
        bdata[cbase[b] + (k - sstart[b])] = stage[k];
    }
}

// ---------------- seed: mark idx nodes (tag 1) ----------------
__global__ void seed_mark(const int* __restrict__ idx, int B, int* __restrict__ mark) {
    int t = threadIdx.x;
    if (t < B) mark[idx[t]] = 1;
}

// ------- expansion 1 + degree count (fused): one block per bucket ----------------
__global__ __launch_bounds__(BTPB) void expand_dis(const unsigned* __restrict__ bdata,
                                                   const int* __restrict__ bucketOff,
                                                   int* __restrict__ mark,
                                                   float* __restrict__ dis, int n) {
    __shared__ unsigned char lm[BNODES];   // 4 KB mark snapshot
    __shared__ int cnt[BNODES];            // 16 KB degree counters
    int b = blockIdx.x, t = threadIdx.x;
    int base = b << 12;
    for (int j = t; j < BNODES; j += BTPB) {
        int node = base + j;
        lm[j] = (unsigned char)((node < n) ? mark[node] : 0);
        cnt[j] = 0;
    }
    __syncthreads();
    int e0 = bucketOff[b], e1 = bucketOff[b + 1];
    for (int k = e0 + t; k < e1; k += BTPB) {
        unsigned p = __builtin_nontemporal_load(&bdata[k]);
        int j = p >> 20;
        atomicAdd(&cnt[j], 1);
        if (lm[j] == 1) {
            int s = (int)(p & 0xFFFFFu);
            if (mark[s] == 0) atomicCAS(&mark[s], 0, 2);
        }
    }
    __syncthreads();
    for (int j = t; j < BNODES; j += BTPB) {
        int node = base + j;
        if (node < n) dis[node] = rsqrtf((float)cnt[j] + 1.0f);
    }
}

// ------- expansion 2/3: one block per bucket; LDS mark snapshot ----------------
__global__ __launch_bounds__(BTPB) void expand_b(const unsigned* __restrict__ bdata,
                                                 const int* __restrict__ bucketOff,
                                                 int* __restrict__ mark, int maxTag,
                                                 int newTag, int n) {
    __shared__ unsigned char lm[BNODES];
    int b = blockIdx.x, t = threadIdx.x;
    int base = b << 12;
    for (int j = t; j < BNODES; j += BTPB) {
        int node = base + j;
        lm[j] = (unsigned char)((node < n) ? mark[node] : 0);
    }
    __syncthreads();
    int e0 = bucketOff[b], e1 = bucketOff[b + 1];
    for (int k = e0 + t; k < e1; k += BTPB) {
        unsigned p = __builtin_nontemporal_load(&bdata[k]);
        int m = lm[p >> 20];
        if (m > 0 && m <= maxTag) {
            int s = (int)(p & 0xFFFFFu);
            if (mark[s] == 0) atomicCAS(&mark[s], 0, newTag);
        }
    }
}

// ---------------- global rank scan over mark (dense rows in node-id order) ------------
__global__ void rank_blocks(const int* __restrict__ mark, int* __restrict__ rank,
                            int* __restrict__ bsum, int n) {
    __shared__ int lds[TPB];
    int i = blockIdx.x * TPB + threadIdx.x;
    int v = (i < n && mark[i] != 0) ? 1 : 0;
    lds[threadIdx.x] = v;
    __syncthreads();
#pragma unroll
    for (int off = 1; off < TPB; off <<= 1) {
        int t = (threadIdx.x >= off) ? lds[threadIdx.x - off] : 0;
        __syncthreads();
        lds[threadIdx.x] += t;
        __syncthreads();
    }
    if (i < n) rank[i] = lds[threadIdx.x] - v;
    if (threadIdx.x == TPB - 1) bsum[blockIdx.x] = lds[TPB - 1];
}

__global__ void bsum_scan(int* __restrict__ bsum, int nb, int* __restrict__ total) {
    __shared__ int lds[TPB];
    int carry = 0;
    for (int base = 0; base < nb; base += TPB) {
        int i = base + threadIdx.x;
        int v = (i < nb) ? bsum[i] : 0;
        lds[threadIdx.x] = v;
        __syncthreads();
        for (int off = 1; off < TPB; off <<= 1) {
            int t = (threadIdx.x >= off) ? lds[threadIdx.x - off] : 0;
            __syncthreads();
            lds[threadIdx.x] += t;
            __syncthreads();
        }
        int incl = lds[threadIdx.x];
        if (i < nb) bsum[i] = carry + incl - v;
        carry += lds[TPB - 1];
        __syncthreads();
    }
    if (threadIdx.x == 0) *total = carry;
}

__global__ void rank_add(int* __restrict__ rank, const int* __restrict__ bsum,
                         const int* __restrict__ mark, int* __restrict__ L,
                         int* __restrict__ T, int n) {
    int i = blockIdx.x * TPB + threadIdx.x;
    if (i >= n) return;
    int r = rank[i] + bsum[blockIdx.x];
    rank[i] = r;
    int m = mark[i];
    if (m) { L[r] = i; T[r] = m; }
}

// ---------------- per-bucket row degree count (marked dst only) ----------------
__global__ __launch_bounds__(BTPB) void count_rows_b(const unsigned* __restrict__ bdata,
                                                     const int* __restrict__ bucketOff,
                                                     const int* __restrict__ mark,
                                                     const int* __restrict__ rank,
                                                     int* __restrict__ rcnt, int n) {
    __shared__ unsigned char lm[BNODES];
    __shared__ int cnt[BNODES];
    int b = blockIdx.x, t = threadIdx.x;
    int base = b << 12;
    for (int j = t; j < BNODES; j += BTPB) {
        int node = base + j;
        lm[j] = (unsigned char)((node < n) ? mark[node] : 0);
        cnt[j] = 0;
    }
    __syncthreads();
    int e0 = bucketOff[b], e1 = bucketOff[b + 1];
    for (int k = e0 + t; k < e1; k += BTPB) {
        unsigned p = __builtin_nontemporal_load(&bdata[k]);
        int j = p >> 20;
        if (lm[j]) atomicAdd(&cnt[j], 1);
    }
    __syncthreads();
    for (int j = t; j < BNODES; j += BTPB) {
        int node = base + j;
        if (node < n && lm[j]) rcnt[rank[node]] = cnt[j];
    }
}

// ---------------- mrp scan over rcnt[0..c2) ----------------
__global__ void mrp_blocks(const int* __restrict__ rcnt, int* __restrict__ mrp,
                           int* __restrict__ bsum, const int* __restrict__ cnts) {
    __shared__ int lds[TPB];
    int c2 = cnts[0];
    int i = blockIdx.x * TPB + threadIdx.x;
    int v = (i < c2) ? rcnt[i] : 0;
    lds[threadIdx.x] = v;
    __syncthreads();
#pragma unroll
    for (int off = 1; off < TPB; off <<= 1) {
        int t = (threadIdx.x >= off) ? lds[threadIdx.x - off] : 0;
        __syncthreads();
        lds[threadIdx.x] += t;
        __syncthreads();
    }
    if (i < c2) mrp[i] = lds[threadIdx.x] - v;
    if (threadIdx.x == TPB - 1) bsum[blockIdx.x] = lds[TPB - 1];
}

__global__ void mrp_add(int* __restrict__ mrp, const int* __restrict__ bsum, int nb,
                        const int* __restrict__ cnts) {
    int c2 = cnts[0];
    int i = blockIdx.x * TPB + threadIdx.x;
    if (i < c2) mrp[i] += bsum[blockIdx.x];
    if (i == 0) mrp[c2] = bsum[nb];     // total filtered edges
}

// ---------------- per-bucket fill into mini-CSR ----------------
__global__ __launch_bounds__(BTPB) void fill_b(const unsigned* __restrict__ bdata,
                                               const int* __restrict__ bucketOff,
                                               const int* __restrict__ mark,
                                               const int* __restrict__ rank,
                                               const int* __restrict__ mrp,
                                               int* __restrict__ mcol, int n) {
    __shared__ unsigned char lm[BNODES];
    __shared__ int cur[BNODES];
    int b = blockIdx.x, t = threadIdx.x;
    int base = b << 12;
    for (int j = t; j < BNODES; j += BTPB) {
        int node = base + j;
        int m = (node < n) ? mark[node] : 0;
        lm[j] = (unsigned char)m;
        cur[j] = m ? mrp[rank[node]] : 0;
    }
    __syncthreads();
    int e0 = bucketOff[b], e1 = bucketOff[b + 1];
    for (int k = e0 + t; k < e1; k += BTPB) {
        unsigned p = __builtin_nontemporal_load(&bdata[k]);
        int j = p >> 20;
        if (lm[j]) {
            int pos = atomicAdd(&cur[j], 1);
            mcol[pos] = (int)(p & 0xFFFFFu);
        }
    }
}

union H8 { uv4 u; __half2 h2[4]; };

// ---------------- layer 1 (all nodes): hs = (x*W1)*dis  (fp16x8) ----------------
__global__ void node_l1(const float* __restrict__ x, const float* __restrict__ W1,
                        const float* __restrict__ dis, __half* __restrict__ hs, int n) {
    int i = blockIdx.x * blockDim.x + threadIdx.x;
    if (i >= n) return;
    float xd = x[i] * dis[i];
    float4 w0 = ((const float4*)W1)[0];
    float4 w1 = ((const float4*)W1)[1];
    H8 o;
    o.h2[0] = __floats2half2_rn(xd * w0.x, xd * w0.y);
    o.h2[1] = __floats2half2_rn(xd * w0.z, xd * w0.w);
    o.h2[2] = __floats2half2_rn(xd * w1.x, xd * w1.y);
    o.h2[3] = __floats2half2_rn(xd * w1.z, xd * w1.w);
    ((uv4*)hs)[i] = o.u;
}

// ---------------- fused pull + node transform over rows with tag <= tagMax ------------
__global__ void pull_tag(const int* __restrict__ L, const int* __restrict__ T,
                         const int* __restrict__ cnts, int tagMax,
                         const int* __restrict__ mrp, const int* __restrict__ mcol,
                         const float* __restrict__ dis, const __half* __restrict__ hs_in,
                         const float* __restrict__ bias, const float* __restrict__ W,
                         __half* __restrict__ hs_out) {
    int r = blockIdx.x * blockDim.x + threadIdx.x;
    if (r >= cnts[0]) return;
    if (T[r] > tagMax) return;
    int u = L[r];
    const uv4* hv = (const uv4*)hs_in;
    H8 p; p.u = hv[u];                       // self term
    float2 a0 = __half22float2(p.h2[0]);
    float2 a1 = __half22float2(p.h2[1]);
    float2 a2 = __half22float2(p.h2[2]);
    float2 a3 = __half22float2(p.h2[3]);
    int s = mrp[r], e = mrp[r + 1];
    for (int k = s; k < e; ++k) {
        H8 q; q.u = hv[mcol[k]];
        float2 b0 = __half22float2(q.h2[0]);
        float2 b1 = __half22float2(q.h2[1]);
        float2 b2 = __half22float2(q.h2[2]);
        float2 b3 = __half22float2(q.h2[3]);
        a0.x += b0.x; a0.y += b0.y; a1.x += b1.x; a1.y += b1.y;
        a2.x += b2.x; a2.y += b2.y; a3.x += b3.x; a3.y += b3.y;
    }
    float d = dis[u];
    float t[8] = {a0.x * d, a0.y * d, a1.x * d, a1.y * d,
                  a2.x * d, a2.y * d, a3.x * d, a3.y * d};
#pragma unroll
    for (int k = 0; k < 8; ++k) {
        float v = t[k] + bias[k];
        t[k] = v > 0.0f ? v : 0.0f;
    }
    float h[8];
#pragma unroll
    for (int j = 0; j < 8; ++j) {
        float acc = 0.0f;
#pragma unroll
        for (int k = 0; k < 8; ++k) acc += t[k] * W[k * 8 + j];
        h[j] = acc * d;
    }
    H8 o;
    o.h2[0] = __floats2half2_rn(h[0], h[1]);
    o.h2[1] = __floats2half2_rn(h[2], h[3]);
    o.h2[2] = __floats2half2_rn(h[4], h[5]);
    o.h2[3] = __floats2half2_rn(h[6], h[7]);
    ((uv4*)hs_out)[u] = o.u;
}

// ---------------- final: out[t][:] = dis*(sum+self) + b4, for the idx nodes ------
__global__ void pull_final(const int* __restrict__ idx, int B, const int* __restrict__ rank,
                           const int* __restrict__ mrp, const int* __restrict__ mcol,
                           const float* __restrict__ dis, const __half* __restrict__ hs_in,
                           const float* __restrict__ b4, float* __restrict__ out) {
    int t = blockIdx.x * blockDim.x + threadIdx.x;
    if (t >= B) return;
    int u = idx[t];
    int rr = rank[u];
    const uv4* hv = (const uv4*)hs_in;
    H8 p; p.u = hv[u];
    float2 a0 = __half22float2(p.h2[0]);
    float2 a1 = __half22float2(p.h2[1]);
    float2 a2 = __half22float2(p.h2[2]);
    float2 a3 = __half22float2(p.h2[3]);
    int s = mrp[rr], e = mrp[rr + 1];
    for (int k = s; k < e; ++k) {
        H8 q; q.u = hv[mcol[k]];
        float2 b0 = __half22float2(q.h2[0]);
        float2 b1 = __half22float2(q.h2[1]);
        float2 b2 = __half22float2(q.h2[2]);
        float2 b3 = __half22float2(q.h2[3]);
        a0.x += b0.x; a0.y += b0.y; a1.x += b1.x; a1.y += b1.y;
        a2.x += b2.x; a2.y += b2.y; a3.x += b3.x; a3.y += b3.y;
    }
    float d = dis[u];
    float* op = out + (size_t)t * 8;
    op[0] = a0.x * d + b4[0]; op[1] = a0.y * d + b4[1];
    op[2] = a1.x * d + b4[2]; op[3] = a1.y * d + b4[3];
    op[4] = a2.x * d + b4[4]; op[5] = a2.y * d + b4[5];
    op[6] = a3.x * d + b4[6]; op[7] = a3.y * d + b4[7];
}

extern "C" void kernel_launch(void* const* d_in, const int* in_sizes, int n_in,
                              void* d_out, int out_size, void* d_ws, size_t ws_size,
                              hipStream_t stream) {
    const float* x   = (const float*)d_in[0];
    const int*   ei  = (const int*)d_in[1];
    const int*   idx = (const int*)d_in[2];
    const float* W1  = (const float*)d_in[3];
    const float* b1  = (const float*)d_in[4];
    const float* W2  = (const float*)d_in[5];
    const float* b2  = (const float*)d_in[6];
    const float* W3  = (const float*)d_in[7];
    const float* b3  = (const float*)d_in[8];
    const float* W4  = (const float*)d_in[9];
    const float* b4  = (const float*)d_in[10];

    const int n = in_sizes[0];      // 1,000,000 nodes (n <= 2^20 for packing)
    const int E = in_sizes[1] / 2;  // 10,000,000 edges
    const int B = in_sizes[2];      // 64 graphs

    const int* src = ei;
    const int* dst = ei + E;

    // workspace (int elements):
    size_t o_mark  = 0;
    size_t o_rank  = o_mark  + (size_t)n;
    size_t o_dis   = o_rank  + (size_t)n;
    size_t o_hsA   = o_dis   + (size_t)n;
    size_t o_hsB   = o_hsA   + (size_t)n * 4;
    size_t o_L     = o_hsB   + (size_t)n * 4;
    size_t o_T     = o_L     + CAP_L;
    size_t o_rcnt  = o_T     + CAP_L;
    size_t o_mrp   = o_rcnt  + CAP_L;
    size_t o_mcol  = o_mrp   + CAP_L + 8;
    size_t o_bd    = o_mcol  + CAP_E;
    size_t o_small = o_bd    + (size_t)E;

    int*      mark      = (int*)d_ws + o_mark;
    int*      rank      = (int*)d_ws + o_rank;
    float*    dis       = (float*)d_ws + o_dis;
    __half*   hsA       = (__half*)((int*)d_ws + o_hsA);
    __half*   hsB       = (__half*)((int*)d_ws + o_hsB);
    int*      L         = (int*)d_ws + o_L;
    int*      T         = (int*)d_ws + o_T;
    int*      rcnt      = (int*)d_ws + o_rcnt;
    int*      mrp       = (int*)d_ws + o_mrp;
    int*      mcol      = (int*)d_ws + o_mcol;
    unsigned* bdata     = (unsigned*)((int*)d_ws + o_bd);
    int*      hist      = (int*)d_ws + o_small;
    int*      bucketOff = hist + NBK;
    int*      tails     = bucketOff + NBK + 8;
    int*      bsum1     = tails + NBK;           // rank-scan block sums (<= 4096+8)
    int*      bsum2     = bsum1 + 4096 + 8;      // mrp-scan block sums (1024+8)
    int*      cnts      = bsum2 + 1024 + 8;      // [0] = c2

    const int NB   = (n + BNODES - 1) / BNODES;            // 245 buckets
    const int gnN  = (n + TPB - 1) / TPB;                  // 3907
    const int gs   = (int)(((long)E + CH - 1) / CH);       // 977
    const int nb2  = CAP_L / TPB;                          // 1024

    // ---- zero init ----
    (void)hipMemsetAsync(mark, 0, (size_t)n * sizeof(int), stream);
    (void)hipMemsetAsync(hist, 0, NBK * sizeof(int), stream);
    (void)hipMemsetAsync(cnts, 0, 8 * sizeof(int), stream);

    // ---- bucket partition (LDS counting sort, burst flush) ----
    hist_buckets<<<1024, TPB, 0, stream>>>(dst, hist, E);
    scan256<<<1, NBK, 0, stream>>>(hist, bucketOff, tails);
    scatter_sort<<<gs, TPB, 0, stream>>>(dst, src, tails, bdata, E);

    // ---- cone expansion (bucket-sequential, LDS marks); expand1 fused with degrees ----
    seed_mark<<<1, 64, 0, stream>>>(idx, B, mark);
    expand_dis<<<NB, BTPB, 0, stream>>>(bdata, bucketOff, mark, dis, n);   // T4 + dis
    expand_b<<<NB, BTPB, 0, stream>>>(bdata, bucketOff, mark, 2, 3, n);    // T3
    expand_b<<<NB, BTPB, 0, stream>>>(bdata, bucketOff, mark, 3, 4, n);    // T2

    // ---- dense rows in node-id order: rank scan ----
    rank_blocks<<<gnN, TPB, 0, stream>>>(mark, rank, bsum1, n);
    bsum_scan<<<1, TPB, 0, stream>>>(bsum1, gnN, &cnts[0]);
    rank_add<<<gnN, TPB, 0, stream>>>(rank, bsum1, mark, L, T, n);

    // ---- mini-CSR: count -> scan -> fill ----
    count_rows_b<<<NB, BTPB, 0, stream>>>(bdata, bucketOff, mark, rank, rcnt, n);
    mrp_blocks<<<nb2, TPB, 0, stream>>>(rcnt, mrp, bsum2, cnts);
    bsum_scan<<<1, TPB, 0, stream>>>(bsum2, nb2, &bsum2[nb2]);
    mrp_add<<<nb2, TPB, 0, stream>>>(mrp, bsum2, nb2, cnts);
    fill_b<<<NB, BTPB, 0, stream>>>(bdata, bucketOff, mark, rank, mrp, mcol, n);

    // ---- layers ----
    node_l1<<<gnN, TPB, 0, stream>>>(x, W1, dis, hsA, n);
    pull_tag<<<nb2, TPB, 0, stream>>>(L, T, cnts, 4, mrp, mcol, dis, hsA, b1, W2, hsB);
    pull_tag<<<nb2, TPB, 0, stream>>>(L, T, cnts, 3, mrp, mcol, dis, hsB, b2, W3, hsA);
    pull_tag<<<nb2, TPB, 0, stream>>>(L, T, cnts, 2, mrp, mcol, dis, hsA, b3, W4, hsB);
    pull_final<<<1, 64, 0, stream>>>(idx, B, rank, mrp, mcol, dis, hsB, b4, (float*)d_out);
}

// Round 13
// 508.528 us; speedup vs baseline: 5.7024x; 1.1904x over previous
//
#include <hip/hip_runtime.h>
#include <hip/hip_fp16.h>

#define TPB 256
#define BTPB 512           // threads for per-bucket kernels
#define NBK 256            // bucket index space (dst >> 12); 245 used
#define BNODES 4096        // nodes per bucket
#define CH 6144            // edges per scatter_sort chunk (35 KB LDS -> 4 blocks/CU)
#define CAPB 45056         // fixed bucket capacity (mean 40960 + 20 sigma)
#define CAP_L 262144       // cone row cap (|T2| ~ 85K mean)
#define CAP_E 1572864      // filtered edge cap (~850K mean)

typedef unsigned int uv4 __attribute__((ext_vector_type(4)));

// ---------------- init: tails[b] = b * CAPB ----------------
__global__ void init_tails(int* __restrict__ tails) {
    tails[threadIdx.x] = threadIdx.x * CAPB;
}

// ------- partition edges into fixed-capacity buckets; LDS counting sort, burst flush ---
// payload: (dstLow12 << 20) | src  (exactly 32 bits; requires n <= 2^20)
__global__ __launch_bounds__(TPB) void scatter_sort(const int* __restrict__ dst,
                                                    const int* __restrict__ src,
                                                    int* __restrict__ tails,
                                                    unsigned* __restrict__ bdata, int nE) {
    __shared__ unsigned      stage[CH];      // 24 KB
    __shared__ unsigned char bkt[CH];        // 6 KB
    __shared__ int cnt[NBK], sstart[NBK], cur[NBK], cbase[NBK];   // 4 KB
    __shared__ int lds[NBK];                 // 1 KB (scan)
    int t = threadIdx.x;
    long base = (long)blockIdx.x * CH;
    int m = (int)(((long)nE - base < CH) ? (nE - base) : CH);
    cnt[t] = 0;
    __syncthreads();
    // pass 1: count
    for (int k = t; k < m; k += TPB)
        atomicAdd(&cnt[__builtin_nontemporal_load(&dst[base + k]) >> 12], 1);
    __syncthreads();
    // exclusive scan cnt -> sstart
    {
        int v = cnt[t];
        lds[t] = v;
        __syncthreads();
        for (int off = 1; off < NBK; off <<= 1) {
            int u = (t >= off) ? lds[t - off] : 0;
            __syncthreads();
            lds[t] += u;
            __syncthreads();
        }
        sstart[t] = lds[t] - v;
        cur[t] = lds[t] - v;
    }
    __syncthreads();
    // pass 2: place into LDS, sorted by bucket
    for (int k = t; k < m; k += TPB) {
        int d = dst[base + k];
        int s = src[base + k];
        int b = d >> 12;
        int pos = atomicAdd(&cur[b], 1);
        stage[pos] = ((unsigned)(d & 4095) << 20) | (unsigned)s;
        bkt[pos] = (unsigned char)b;
    }
    __syncthreads();
    // reserve global runs
    cbase[t] = cnt[t] ? atomicAdd(&tails[t], cnt[t]) : 0;
    __syncthreads();
    // burst flush: consecutive threads -> consecutive dests; lines filled promptly
    for (int k = t; k < m; k += TPB) {
        int b = bkt[k];
        bdata[cbase[b] + (k - sstart[b])] = stage[k];
    }
}

// ---------------- seed: mark idx nodes (tag 1) ----------------
__global__ void seed_mark(const int* __restrict__ idx, int B, int* __restrict__ mark) {
    int t = threadIdx.x;
    if (t < B) mark[idx[t]] = 1;
}

// ------- expansion 1 + degree count (fused): one block per bucket ----------------
__global__ __launch_bounds__(BTPB) void expand_dis(const unsigned* __restrict__ bdata,
                                                   const int* __restrict__ tails,
                                                   int* __restrict__ mark,
                                                   float* __restrict__ dis, int n) {
    __shared__ unsigned char lm[BNODES];   // 4 KB mark snapshot
    __shared__ int cnt[BNODES];            // 16 KB degree counters
    int b = blockIdx.x, t = threadIdx.x;
    int base = b << 12;
    for (int j = t; j < BNODES; j += BTPB) {
        int node = base + j;
        lm[j] = (unsigned char)((node < n) ? mark[node] : 0);
        cnt[j] = 0;
    }
    __syncthreads();
    int e0 = b * CAPB, e1 = tails[b];
    for (int k = e0 + t; k < e1; k += BTPB) {
        unsigned p = __builtin_nontemporal_load(&bdata[k]);
        int j = p >> 20;
        atomicAdd(&cnt[j], 1);
        if (lm[j] == 1) {
            int s = (int)(p & 0xFFFFFu);
            if (mark[s] == 0) atomicCAS(&mark[s], 0, 2);
        }
    }
    __syncthreads();
    for (int j = t; j < BNODES; j += BTPB) {
        int node = base + j;
        if (node < n) dis[node] = rsqrtf((float)cnt[j] + 1.0f);
    }
}

// ------- expansion 2/3: one block per bucket; LDS mark snapshot ----------------
__global__ __launch_bounds__(BTPB) void expand_b(const unsigned* __restrict__ bdata,
                                                 const int* __restrict__ tails,
                                                 int* __restrict__ mark, int maxTag,
                                                 int newTag, int n) {
    __shared__ unsigned char lm[BNODES];
    int b = blockIdx.x, t = threadIdx.x;
    int base = b << 12;
    for (int j = t; j < BNODES; j += BTPB) {
        int node = base + j;
        lm[j] = (unsigned char)((node < n) ? mark[node] : 0);
    }
    __syncthreads();
    int e0 = b * CAPB, e1 = tails[b];
    for (int k = e0 + t; k < e1; k += BTPB) {
        unsigned p = __builtin_nontemporal_load(&bdata[k]);
        int m = lm[p >> 20];
        if (m > 0 && m <= maxTag) {
            int s = (int)(p & 0xFFFFFu);
            if (mark[s] == 0) atomicCAS(&mark[s], 0, newTag);
        }
    }
}

// ---------------- global rank scan over mark (dense rows in node-id order) ------------
__global__ void rank_blocks(const int* __restrict__ mark, int* __restrict__ rank,
                            int* __restrict__ bsum, int n) {
    __shared__ int lds[TPB];
    int i = blockIdx.x * TPB + threadIdx.x;
    int v = (i < n && mark[i] != 0) ? 1 : 0;
    lds[threadIdx.x] = v;
    __syncthreads();
#pragma unroll
    for (int off = 1; off < TPB; off <<= 1) {
        int t = (threadIdx.x >= off) ? lds[threadIdx.x - off] : 0;
        __syncthreads();
        lds[threadIdx.x] += t;
        __syncthreads();
    }
    if (i < n) rank[i] = lds[threadIdx.x] - v;
    if (threadIdx.x == TPB - 1) bsum[blockIdx.x] = lds[TPB - 1];
}

__global__ void bsum_scan(int* __restrict__ bsum, int nb, int* __restrict__ total) {
    __shared__ int lds[TPB];
    int carry = 0;
    for (int base = 0; base < nb; base += TPB) {
        int i = base + threadIdx.x;
        int v = (i < nb) ? bsum[i] : 0;
        lds[threadIdx.x] = v;
        __syncthreads();
        for (int off = 1; off < TPB; off <<= 1) {
            int t = (threadIdx.x >= off) ? lds[threadIdx.x - off] : 0;
            __syncthreads();
            lds[threadIdx.x] += t;
            __syncthreads();
        }
        int incl = lds[threadIdx.x];
        if (i < nb) bsum[i] = carry + incl - v;
        carry += lds[TPB - 1];
        __syncthreads();
    }
    if (threadIdx.x == 0) *total = carry;
}

// rank finalize + emit row lists; rcnt[r] = deg(u) recovered exactly from dis
__global__ void rank_add(int* __restrict__ rank, const int* __restrict__ bsum,
                         const int* __restrict__ mark, const float* __restrict__ dis,
                         int* __restrict__ L, int* __restrict__ T,
                         int* __restrict__ rcnt, int n) {
    int i = blockIdx.x * TPB + threadIdx.x;
    if (i >= n) return;
    int r = rank[i] + bsum[blockIdx.x];
    rank[i] = r;
    int m = mark[i];
    if (m) {
        L[r] = i; T[r] = m;
        float d = dis[i];
        rcnt[r] = (int)roundf(1.0f / (d * d)) - 1;   // = in-degree (exact; deg <= ~60)
    }
}

// ---------------- mrp scan over rcnt[0..c2) ----------------
__global__ void mrp_blocks(const int* __restrict__ rcnt, int* __restrict__ mrp,
                           int* __restrict__ bsum, const int* __restrict__ cnts) {
    __shared__ int lds[TPB];
    int c2 = cnts[0];
    int i = blockIdx.x * TPB + threadIdx.x;
    int v = (i < c2) ? rcnt[i] : 0;
    lds[threadIdx.x] = v;
    __syncthreads();
#pragma unroll
    for (int off = 1; off < TPB; off <<= 1) {
        int t = (threadIdx.x >= off) ? lds[threadIdx.x - off] : 0;
        __syncthreads();
        lds[threadIdx.x] += t;
        __syncthreads();
    }
    if (i < c2) mrp[i] = lds[threadIdx.x] - v;
    if (threadIdx.x == TPB - 1) bsum[blockIdx.x] = lds[TPB - 1];
}

__global__ void mrp_add(int* __restrict__ mrp, const int* __restrict__ bsum, int nb,
                        const int* __restrict__ cnts) {
    int c2 = cnts[0];
    int i = blockIdx.x * TPB + threadIdx.x;
    if (i < c2) mrp[i] += bsum[blockIdx.x];
    if (i == 0) mrp[c2] = bsum[nb];     // total filtered edges
}

// ---------------- per-bucket fill into mini-CSR ----------------
__global__ __launch_bounds__(BTPB) void fill_b(const unsigned* __restrict__ bdata,
                                               const int* __restrict__ tails,
                                               const int* __restrict__ mark,
                                               const int* __restrict__ rank,
                                               const int* __restrict__ mrp,
                                               int* __restrict__ mcol, int n) {
    __shared__ unsigned char lm[BNODES];
    __shared__ int cur[BNODES];
    int b = blockIdx.x, t = threadIdx.x;
    int base = b << 12;
    for (int j = t; j < BNODES; j += BTPB) {
        int node = base + j;
        int m = (node < n) ? mark[node] : 0;
        lm[j] = (unsigned char)m;
        cur[j] = m ? mrp[rank[node]] : 0;
    }
    __syncthreads();
    int e0 = b * CAPB, e1 = tails[b];
    for (int k = e0 + t; k < e1; k += BTPB) {
        unsigned p = __builtin_nontemporal_load(&bdata[k]);
        int j = p >> 20;
        if (lm[j]) {
            int pos = atomicAdd(&cur[j], 1);
            mcol[pos] = (int)(p & 0xFFFFFu);
        }
    }
}

union H8 { uv4 u; __half2 h2[4]; };

// ---------------- layer 1 (all nodes): hs = (x*W1)*dis  (fp16x8) ----------------
__global__ void node_l1(const float* __restrict__ x, const float* __restrict__ W1,
                        const float* __restrict__ dis, __half* __restrict__ hs, int n) {
    int i = blockIdx.x * blockDim.x + threadIdx.x;
    if (i >= n) return;
    float xd = x[i] * dis[i];
    float4 w0 = ((const float4*)W1)[0];
    float4 w1 = ((const float4*)W1)[1];
    H8 o;
    o.h2[0] = __floats2half2_rn(xd * w0.x, xd * w0.y);
    o.h2[1] = __floats2half2_rn(xd * w0.z, xd * w0.w);
    o.h2[2] = __floats2half2_rn(xd * w1.x, xd * w1.y);
    o.h2[3] = __floats2half2_rn(xd * w1.z, xd * w1.w);
    ((uv4*)hs)[i] = o.u;
}

// ---------------- fused pull + node transform over rows with tag <= tagMax ------------
__global__ void pull_tag(const int* __restrict__ L, const int* __restrict__ T,
                         const int* __restrict__ cnts, int tagMax,
                         const int* __restrict__ mrp, const int* __restrict__ mcol,
                         const float* __restrict__ dis, const __half* __restrict__ hs_in,
                         const float* __restrict__ bias, const float* __restrict__ W,
                         __half* __restrict__ hs_out) {
    int r = blockIdx.x * blockDim.x + threadIdx.x;
    if (r >= cnts[0]) return;
    if (T[r] > tagMax) return;
    int u = L[r];
    const uv4* hv = (const uv4*)hs_in;
    H8 p; p.u = hv[u];                       // self term
    float2 a0 = __half22float2(p.h2[0]);
    float2 a1 = __half22float2(p.h2[1]);
    float2 a2 = __half22float2(p.h2[2]);
    float2 a3 = __half22float2(p.h2[3]);
    int s = mrp[r], e = mrp[r + 1];
    for (int k = s; k < e; ++k) {
        H8 q; q.u = hv[mcol[k]];
        float2 b0 = __half22float2(q.h2[0]);
        float2 b1 = __half22float2(q.h2[1]);
        float2 b2 = __half22float2(q.h2[2]);
        float2 b3 = __half22float2(q.h2[3]);
        a0.x += b0.x; a0.y += b0.y; a1.x += b1.x; a1.y += b1.y;
        a2.x += b2.x; a2.y += b2.y; a3.x += b3.x; a3.y += b3.y;
    }
    float d = dis[u];
    float t[8] = {a0.x * d, a0.y * d, a1.x * d, a1.y * d,
                  a2.x * d, a2.y * d, a3.x * d, a3.y * d};
#pragma unroll
    for (int k = 0; k < 8; ++k) {
        float v = t[k] + bias[k];
        t[k] = v > 0.0f ? v : 0.0f;
    }
    float h[8];
#pragma unroll
    for (int j = 0; j < 8; ++j) {
        float acc = 0.0f;
#pragma unroll
        for (int k = 0; k < 8; ++k) acc += t[k] * W[k * 8 + j];
        h[j] = acc * d;
    }
    H8 o;
    o.h2[0] = __floats2half2_rn(h[0], h[1]);
    o.h2[1] = __floats2half2_rn(h[2], h[3]);
    o.h2[2] = __floats2half2_rn(h[4], h[5]);
    o.h2[3] = __floats2half2_rn(h[6], h[7]);
    ((uv4*)hs_out)[u] = o.u;
}

// ---------------- final: out[t][:] = dis*(sum+self) + b4, for the idx nodes ------
__global__ void pull_final(const int* __restrict__ idx, int B, const int* __restrict__ rank,
                           const int* __restrict__ mrp, const int* __restrict__ mcol,
                           const float* __restrict__ dis, const __half* __restrict__ hs_in,
                           const float* __restrict__ b4, float* __restrict__ out) {
    int t = blockIdx.x * blockDim.x + threadIdx.x;
    if (t >= B) return;
    int u = idx[t];
    int rr = rank[u];
    const uv4* hv = (const uv4*)hs_in;
    H8 p; p.u = hv[u];
    float2 a0 = __half22float2(p.h2[0]);
    float2 a1 = __half22float2(p.h2[1]);
    float2 a2 = __half22float2(p.h2[2]);
    float2 a3 = __half22float2(p.h2[3]);
    int s = mrp[rr], e = mrp[rr + 1];
    for (int k = s; k < e; ++k) {
        H8 q; q.u = hv[mcol[k]];
        float2 b0 = __half22float2(q.h2[0]);
        float2 b1 = __half22float2(q.h2[1]);
        float2 b2 = __half22float2(q.h2[2]);
        float2 b3 = __half22float2(q.h2[3]);
        a0.x += b0.x; a0.y += b0.y; a1.x += b1.x; a1.y += b1.y;
        a2.x += b2.x; a2.y += b2.y; a3.x += b3.x; a3.y += b3.y;
    }
    float d = dis[u];
    float* op = out + (size_t)t * 8;
    op[0] = a0.x * d + b4[0]; op[1] = a0.y * d + b4[1];
    op[2] = a1.x * d + b4[2]; op[3] = a1.y * d + b4[3];
    op[4] = a2.x * d + b4[4]; op[5] = a2.y * d + b4[5];
    op[6] = a3.x * d + b4[6]; op[7] = a3.y * d + b4[7];
}

extern "C" void kernel_launch(void* const* d_in, const int* in_sizes, int n_in,
                              void* d_out, int out_size, void* d_ws, size_t ws_size,
                              hipStream_t stream) {
    const float* x   = (const float*)d_in[0];
    const int*   ei  = (const int*)d_in[1];
    const int*   idx = (const int*)d_in[2];
    const float* W1  = (const float*)d_in[3];
    const float* b1  = (const float*)d_in[4];
    const float* W2  = (const float*)d_in[5];
    const float* b2  = (const float*)d_in[6];
    const float* W3  = (const float*)d_in[7];
    const float* b3  = (const float*)d_in[8];
    const float* W4  = (const float*)d_in[9];
    const float* b4  = (const float*)d_in[10];

    const int n = in_sizes[0];      // 1,000,000 nodes (n <= 2^20 for packing)
    const int E = in_sizes[1] / 2;  // 10,000,000 edges
    const int B = in_sizes[2];      // 64 graphs

    const int* src = ei;
    const int* dst = ei + E;

    const int NB = (n + BNODES - 1) / BNODES;              // 245 buckets

    // workspace (int elements):
    size_t o_mark  = 0;
    size_t o_rank  = o_mark  + (size_t)n;
    size_t o_dis   = o_rank  + (size_t)n;
    size_t o_hsA   = o_dis   + (size_t)n;
    size_t o_hsB   = o_hsA   + (size_t)n * 4;
    size_t o_L     = o_hsB   + (size_t)n * 4;
    size_t o_T     = o_L     + CAP_L;
    size_t o_rcnt  = o_T     + CAP_L;
    size_t o_mrp   = o_rcnt  + CAP_L;
    size_t o_mcol  = o_mrp   + CAP_L + 8;
    size_t o_bd    = o_mcol  + CAP_E;
    size_t o_small = o_bd    + (size_t)NB * CAPB;

    int*      mark  = (int*)d_ws + o_mark;
    int*      rank  = (int*)d_ws + o_rank;
    float*    dis   = (float*)d_ws + o_dis;
    __half*   hsA   = (__half*)((int*)d_ws + o_hsA);
    __half*   hsB   = (__half*)((int*)d_ws + o_hsB);
    int*      L     = (int*)d_ws + o_L;
    int*      T     = (int*)d_ws + o_T;
    int*      rcnt  = (int*)d_ws + o_rcnt;
    int*      mrp   = (int*)d_ws + o_mrp;
    int*      mcol  = (int*)d_ws + o_mcol;
    unsigned* bdata = (unsigned*)((int*)d_ws + o_bd);
    int*      tails = (int*)d_ws + o_small;
    int*      bsum1 = tails + NBK + 8;           // rank-scan block sums (<= 4096+8)
    int*      bsum2 = bsum1 + 4096 + 8;          // mrp-scan block sums (1024+8)
    int*      cnts  = bsum2 + 1024 + 8;          // [0] = c2

    const int gnN = (n + TPB - 1) / TPB;                   // 3907
    const int gs  = (int)(((long)E + CH - 1) / CH);        // 1628
    const int nb2 = CAP_L / TPB;                           // 1024

    // ---- init ----
    (void)hipMemsetAsync(mark, 0, (size_t)n * sizeof(int), stream);
    init_tails<<<1, NBK, 0, stream>>>(tails);

    // ---- bucket partition (fixed-capacity, LDS counting sort, burst flush) ----
    scatter_sort<<<gs, TPB, 0, stream>>>(dst, src, tails, bdata, E);

    // ---- cone expansion (bucket-sequential, LDS marks); expand1 fused with degrees ----
    seed_mark<<<1, 64, 0, stream>>>(idx, B, mark);
    expand_dis<<<NB, BTPB, 0, stream>>>(bdata, tails, mark, dis, n);    // T4 + dis
    expand_b<<<NB, BTPB, 0, stream>>>(bdata, tails, mark, 2, 3, n);     // T3
    expand_b<<<NB, BTPB, 0, stream>>>(bdata, tails, mark, 3, 4, n);     // T2

    // ---- dense rows in node-id order: rank scan; rcnt from dis (deg) ----
    rank_blocks<<<gnN, TPB, 0, stream>>>(mark, rank, bsum1, n);
    bsum_scan<<<1, TPB, 0, stream>>>(bsum1, gnN, &cnts[0]);
    rank_add<<<gnN, TPB, 0, stream>>>(rank, bsum1, mark, dis, L, T, rcnt, n);

    // ---- mini-CSR: scan -> fill ----
    mrp_blocks<<<nb2, TPB, 0, stream>>>(rcnt, mrp, bsum2, cnts);
    bsum_scan<<<1, TPB, 0, stream>>>(bsum2, nb2, &bsum2[nb2]);
    mrp_add<<<nb2, TPB, 0, stream>>>(mrp, bsum2, nb2, cnts);
    fill_b<<<NB, BTPB, 0, stream>>>(bdata, tails, mark, rank, mrp, mcol, n);

    // ---- layers ----
    node_l1<<<gnN, TPB, 0, stream>>>(x, W1, dis, hsA, n);
    pull_tag<<<nb2, TPB, 0, stream>>>(L, T, cnts, 4, mrp, mcol, dis, hsA, b1, W2, hsB);
    pull_tag<<<nb2, TPB, 0, stream>>>(L, T, cnts, 3, mrp, mcol, dis, hsB, b2, W3, hsA);
    pull_tag<<<nb2, TPB, 0, stream>>>(L, T, cnts, 2, mrp, mcol, dis, hsA, b3, W4, hsB);
    pull_final<<<1, 64, 0, stream>>>(idx, B, rank, mrp, mcol, dis, hsB, b4, (float*)d_out);
}